// Round 10
// baseline (554.758 us; speedup 1.0000x reference)
//
#include <hip/hip_runtime.h>

#define Bc 32
#define Kc 64
#define Wc 100
#define Hc 150
#define H3c 450
#define KWc 6400
#define ALPHAc 0.2f
#define THRESc 0.0002f

typedef unsigned int u32;
typedef unsigned short u16;
typedef unsigned long long u64;
typedef __attribute__((ext_vector_type(8))) short short8;   // 8 bf16
typedef __attribute__((ext_vector_type(4))) float floatx4;  // 4 f32 acc

// ---- ws layout (float offsets), 4.55 MB ----
#define OFF_WX      0u          // 204800  Wx (B,K,W) fp32
#define OFF_CS      204800u     // 2048    causesum (B,K)
#define OFF_GX      206848u     // 921600  gl proj (s,b,g)
#define OFF_HT      1128448u    // 4800    h_t (B,H)
#define OFF_Z       1133248u    // 4800    z (B,H)

__device__ __forceinline__ float us2f(u16 u){ u32 x=((u32)u)<<16; return __uint_as_float(x); }
__device__ __forceinline__ u16 f2us(float f){
  u32 x = __float_as_uint(f);
  u32 r = (x + 0x7fffu + ((x>>16)&1u)) >> 16;   // RNE bf16
  return (u16)r;
}

// LDS-only barrier: skips the vmcnt(0) drain __syncthreads would emit; global
// loads issued before it stay in flight across it (consumed via register deps).
__device__ __forceinline__ void lds_barrier(){
  __builtin_amdgcn_sched_barrier(0);
  asm volatile("s_waitcnt lgkmcnt(0)" ::: "memory");
  __builtin_amdgcn_s_barrier();
  __builtin_amdgcn_sched_barrier(0);
}

// ---------- Wx = x @ lin_w.T + lin_b ----------
__global__ void wx_kernel(const float* __restrict__ x, const float* __restrict__ lin_w,
                          const float* __restrict__ lin_b, float* __restrict__ ws){
  int o = blockIdx.x*256 + threadIdx.x;
  if (o >= Bc*KWc) return;
  int i = o % Wc;
  int bk = o / Wc;
  const float4* xr = (const float4*)(x + bk*Wc);
  const float4* wr = (const float4*)(lin_w + i*Wc);
  float acc = lin_b[i];
  #pragma unroll
  for (int j=0;j<25;j++){
    float4 xv = xr[j], wv = wr[j];
    acc += xv.x*wv.x + xv.y*wv.y + xv.z*wv.z + xv.w*wv.w;
  }
  ws[OFF_WX + o] = acc;
}

// ---------- attention softmax + thresholded sum (float4, __expf, log-threshold) ----------
__global__ void attn_kernel(const float* __restrict__ y, const float* __restrict__ a,
                            const float* __restrict__ bias, float* __restrict__ ws){
  __shared__ __align__(16) float e_l[KWc];
  __shared__ float red[4];
  int row = blockIdx.x;          // b*64 + k
  int b = row >> 6, k = row & 63;
  int tid = threadIdx.x;
  float a0 = a[0], a1 = a[1];
  float yv = y[row];
  const float4* v4  = (const float4*)(ws + OFF_WX + (size_t)b*KWc);
  const float4* br4 = (const float4*)(bias + (size_t)k*KWc);
  float4* e4 = (float4*)e_l;
  float ay = a0*yv;
  float m = -3.4e38f;
  for (int j=tid; j<KWc/4; j+=256){
    float4 vv = v4[j], bb = br4[j];
    float4 e;
    e.x = ay + a1*vv.x + bb.x; e.x = (e.x>=0.f)?e.x:ALPHAc*e.x;
    e.y = ay + a1*vv.y + bb.y; e.y = (e.y>=0.f)?e.y:ALPHAc*e.y;
    e.z = ay + a1*vv.z + bb.z; e.z = (e.z>=0.f)?e.z:ALPHAc*e.z;
    e.w = ay + a1*vv.w + bb.w; e.w = (e.w>=0.f)?e.w:ALPHAc*e.w;
    e4[j] = e;
    m = fmaxf(m, fmaxf(fmaxf(e.x,e.y), fmaxf(e.z,e.w)));
  }
  for (int o=32;o;o>>=1) m = fmaxf(m, __shfl_down(m, o));
  if ((tid&63)==0) red[tid>>6] = m;
  __syncthreads();
  m = fmaxf(fmaxf(red[0],red[1]), fmaxf(red[2],red[3]));
  __syncthreads();
  float ssum = 0.f;
  for (int j=tid; j<KWc/4; j+=256){
    float4 e = e4[j];
    ssum += __expf(e.x-m) + __expf(e.y-m) + __expf(e.z-m) + __expf(e.w-m);
  }
  for (int o=32;o;o>>=1) ssum += __shfl_down(ssum, o);
  if ((tid&63)==0) red[tid>>6] = ssum;
  __syncthreads();
  float s = red[0]+red[1]+red[2]+red[3];
  float thr = m + logf(THRESc * s);
  float cs = 0.f;
  for (int j=tid; j<KWc/4; j+=256){
    float4 e = e4[j];
    float4 vv = v4[j];
    if (e.x >= thr) cs += vv.x;
    if (e.y >= thr) cs += vv.y;
    if (e.z >= thr) cs += vv.z;
    if (e.w >= thr) cs += vv.w;
  }
  for (int o=32;o;o>>=1) cs += __shfl_down(cs, o);
  if ((tid&63)==0) red[tid>>6] = cs;
  __syncthreads();
  if (tid==0) ws[OFF_CS + row] = red[0]+red[1]+red[2]+red[3];
}

// ---------- gl input projection ----------
__global__ void glproj_kernel(const float* __restrict__ gl_wih, const float* __restrict__ gl_bih,
                              float* __restrict__ ws){
  int o = blockIdx.x*256 + threadIdx.x;
  if (o >= Kc*Bc*H3c) return;
  int g = o % H3c;
  int t = o / H3c;               // s*32 + b
  int b = t & 31, s = t >> 5;
  float cs = ws[OFF_CS + b*Kc + s];
  const float4* xr = (const float4*)(ws + OFF_WX + b*KWc + s*Wc);
  const float4* wr = (const float4*)(gl_wih + g*Wc);
  float acc = gl_bih[g];
  #pragma unroll
  for (int j=0;j<25;j++){
    float4 wv = wr[j], xv = xr[j];
    acc += (xv.x+cs)*wv.x + (xv.y+cs)*wv.y + (xv.z+cs)*wv.z + (xv.w+cs)*wv.w;
  }
  ws[OFF_GX + o] = acc;
}

// ---------- gl recurrent GRU v12: wave-owns-row-range, hi/lo-packed cols, 1 barrier/step ----------
// 640 thr / 10 waves; wave w owns rows w*16..+15 of r,z,n sections (tiles sec*10+w).
// B cols 0-7 = h_hi batches, 8-15 = h_lo -> whh chunks 10->5; shfl_xor(8) merges halves.
// Gates fully in-register (r,z,nh in same lane), h_prev in regs, double-buffered h LDS.
__global__ void __launch_bounds__(640,1) glgru4_kernel(
    const float* __restrict__ gl_whh, const float* __restrict__ gl_bhh,
    float* __restrict__ ws){
  __shared__ __align__(16) u16 bF[20*16*40];   // 2 bufs x 10 chunks x [col16][40]
  int b0 = blockIdx.x*8;
  int tid = threadIdx.x;
  int w = tid >> 6, lane = tid & 63, quad = lane >> 4, n16 = lane & 15;
  int range = w;                               // 0..9
  int t0 = range*16 + quad*4;

  // A fragments: 3 sections x 5 chunks for this wave's 16-row range
  short8 whhA[3][5];
  #pragma unroll
  for (int sec=0; sec<3; sec++){
    int sr = range*16 + n16;
    bool rowok = (sr < Hc);
    const float* wr = gl_whh + (size_t)(sec*Hc + sr)*Hc;
    #pragma unroll
    for (int c=0;c<5;c++){
      union { short8 v; u16 u[8]; } t8;
      #pragma unroll
      for (int j=0;j<8;j++){
        int k = c*32 + quad*8 + j;
        float v = (rowok && k < Hc) ? wr[k] : 0.f;
        t8.u[j] = f2us(v);
      }
      whhA[sec][c] = t8.v;
    }
  }
  for (int i=tid; i<20*640/2; i+=640) ((u32*)bF)[i] = 0u;   // h(0)=0

  float bh_r[4], bh_z[4], bh_n[4], hprev[4];
  #pragma unroll
  for (int r=0;r<4;r++){
    int t = t0 + r;
    bool ok = (t < Hc);
    bh_r[r] = ok ? gl_bhh[t]      : 0.f;
    bh_z[r] = ok ? gl_bhh[Hc+t]   : 0.f;
    bh_n[r] = ok ? gl_bhh[2*Hc+t] : 0.f;
    hprev[r] = 0.f;
  }

  for (int s=0;s<Kc;s++){
    int rb = s & 1, wb = rb ^ 1;
    // gx loads issued BEFORE the lgkm-only barrier -> in flight across it
    float gxr[4], gxz[4], gxn[4];
    if (n16 < 8){
      const float* gp = ws + OFF_GX + (size_t)(s*Bc + b0 + n16)*H3c;
      #pragma unroll
      for (int r=0;r<4;r++){
        int t = t0 + r;
        bool ok = (t < Hc);
        gxr[r] = ok ? gp[t]      : 0.f;
        gxz[r] = ok ? gp[Hc+t]   : 0.f;
        gxn[r] = ok ? gp[2*Hc+t] : 0.f;
      }
    }
    lds_barrier();
    const u16* hBase = bF + (size_t)rb*6400 + (size_t)(n16&7)*40 + (size_t)(n16>>3)*3200 + (size_t)quad*8;
    short8 bh[5];
    #pragma unroll
    for (int c=0;c<5;c++) bh[c] = *(const short8*)(hBase + (size_t)c*640);
    floatx4 accR={0.f,0.f,0.f,0.f}, accZ={0.f,0.f,0.f,0.f}, accNH={0.f,0.f,0.f,0.f};
    #pragma unroll
    for (int c=0;c<5;c++){
      accR  = __builtin_amdgcn_mfma_f32_16x16x32_bf16(whhA[0][c], bh[c], accR, 0,0,0);
      accZ  = __builtin_amdgcn_mfma_f32_16x16x32_bf16(whhA[1][c], bh[c], accZ, 0,0,0);
      accNH = __builtin_amdgcn_mfma_f32_16x16x32_bf16(whhA[2][c], bh[c], accNH, 0,0,0);
    }
    #pragma unroll
    for (int r=0;r<4;r++){
      accR[r]  += __shfl_xor(accR[r], 8);
      accZ[r]  += __shfl_xor(accZ[r], 8);
      accNH[r] += __shfl_xor(accNH[r], 8);
    }
    if (n16 < 8){
      float hout[4];
      #pragma unroll
      for (int r=0;r<4;r++){
        float a_r = gxr[r] + accR[r] + bh_r[r];
        float a_z = gxz[r] + accZ[r] + bh_z[r];
        float rr = 1.f/(1.f+__expf(-a_r));
        float zz = 1.f/(1.f+__expf(-a_z));
        float nx = gxn[r] + rr*(accNH[r] + bh_n[r]);
        nx = fminf(fmaxf(nx,-15.f),15.f);
        float e2 = __expf(2.f*nx);
        float n = (e2-1.f)/(e2+1.f);
        float h = (1.f-zz)*n + zz*hprev[r];
        hprev[r] = h; hout[r] = h;
      }
      u16 h0=f2us(hout[0]), h1=f2us(hout[1]), h2=f2us(hout[2]), h3=f2us(hout[3]);
      u16 l0=f2us(hout[0]-us2f(h0)), l1=f2us(hout[1]-us2f(h1));
      u16 l2=f2us(hout[2]-us2f(h2)), l3=f2us(hout[3]-us2f(h3));
      u64 hiP = (u64)h0 | ((u64)h1<<16) | ((u64)h2<<32) | ((u64)h3<<48);
      u64 loP = (u64)l0 | ((u64)l1<<16) | ((u64)l2<<32) | ((u64)l3<<48);
      u32 wbase = (u32)wb*6400u + (u32)(t0>>5)*640u + (u32)n16*40u + (u32)(t0&31);
      *(u64*)(bF + wbase)        = hiP;    // rows 150-159 garbage OK: A k-guard zeros them
      *(u64*)(bF + wbase + 3200) = loP;
    }
  }
  if (n16 < 8){
    #pragma unroll
    for (int r=0;r<4;r++){
      int t = t0 + r;
      if (t < Hc) ws[OFF_HT + (size_t)(b0+n16)*Hc + t] = hprev[r];
    }
  }
}

// ---------- z = mu + sigma * z_noise ----------
__global__ void z_kernel(const float* __restrict__ z_noise, const float* __restrict__ mu_w,
                         const float* __restrict__ mu_b, const float* __restrict__ std_w,
                         const float* __restrict__ std_b, float* __restrict__ ws){
  int o = blockIdx.x*256 + threadIdx.x;
  if (o >= Bc*Hc) return;
  int t = o % Hc, b = o / Hc;
  const float* h = ws + OFF_HT + b*Hc;
  const float2* mwr = (const float2*)(mu_w + t*Hc);
  const float2* swr = (const float2*)(std_w + t*Hc);
  float mu = mu_b[t], lv = std_b[t];
  for (int j=0;j<Hc/2;j++){
    float2 mw = mwr[j], sw = swr[j];
    float h0 = h[2*j], h1 = h[2*j+1];
    mu += h0*mw.x + h1*mw.y;
    lv += h0*sw.x + h1*sw.y;
  }
  float sg = expf(0.5f*lv);
  ws[OFF_Z + o] = mu + sg*z_noise[o];
}

// ---------- causes v12: wave-owns-row-range, hi/lo-packed cols, in-register gates ----------
// 640 thr / 10 waves; wave w owns rows w*16..+15 of r,z,n sections. 27 MFMA/wave/step
// (12 wih + 15 whh) vs 56 before. One barrier/step; double-buffered h+x LDS.
__global__ void __launch_bounds__(640,1) causes3_kernel(
    const float* __restrict__ net_wih, const float* __restrict__ net_whh,
    const float* __restrict__ net_bih, const float* __restrict__ net_bhh,
    const float* __restrict__ ws, float* __restrict__ out){
  __shared__ __align__(16) u16 bF[28*16*40];   // h: 2x10 chunks; x: 2x4 chunks @ 20*640
  const u32 XB = 20*640u;
  int kk = blockIdx.x & 63, bg = blockIdx.x >> 6, b0 = bg*8;
  int tid = threadIdx.x;
  int w = tid >> 6, lane = tid & 63, quad = lane >> 4, n16 = lane & 15;
  int range = w;                                // 0..9
  int t0 = range*16 + quad*4;
  const float* whhk = net_whh + (size_t)kk*H3c*Hc;
  const float* wihk = net_wih + (size_t)kk*H3c*Wc;
  const float* bihk = net_bih + kk*H3c;
  const float* bhhk = net_bhh + kk*H3c;

  short8 whhA[3][5], wihA[3][4];
  #pragma unroll
  for (int sec=0; sec<3; sec++){
    int sr = range*16 + n16;
    bool rowok = (sr < Hc);
    const float* wr  = whhk + (size_t)(sec*Hc + sr)*Hc;
    const float* wr2 = wihk + (size_t)(sec*Hc + sr)*Wc;
    #pragma unroll
    for (int c=0;c<5;c++){
      union { short8 v; u16 u[8]; } t8;
      #pragma unroll
      for (int j=0;j<8;j++){
        int k = c*32 + quad*8 + j;
        float v = (rowok && k < Hc) ? wr[k] : 0.f;
        t8.u[j] = f2us(v);
      }
      whhA[sec][c] = t8.v;
    }
    #pragma unroll
    for (int c=0;c<4;c++){
      union { short8 v; u16 u[8]; } t8;
      #pragma unroll
      for (int j=0;j<8;j++){
        int k = c*32 + quad*8 + j;
        float v = (rowok && k < Wc) ? wr2[k] : 0.f;
        t8.u[j] = f2us(v);
      }
      wihA[sec][c] = t8.v;
    }
  }

  for (int i=tid; i<28*640/2; i+=640) ((u32*)bF)[i] = 0u;

  // per-lane row state: biases + h_prev (batch = n16 when <8)
  float brz_r[4], brz_z[4], bnp_[4], bnh_[4], hprev[4];
  #pragma unroll
  for (int r=0;r<4;r++){
    int t = t0 + r;
    bool ok = (t < Hc);
    brz_r[r] = ok ? (bhhk[t]      + bihk[t])      : 0.f;
    brz_z[r] = ok ? (bhhk[Hc+t]   + bihk[Hc+t])   : 0.f;
    bnh_[r]  = ok ? bhhk[2*Hc+t] : 0.f;
    bnp_[r]  = ok ? bihk[2*Hc+t] : 0.f;
    hprev[r] = (ok && n16 < 8) ? ws[OFF_Z + (size_t)(b0+n16)*Hc + t] : 0.f;
  }
  __syncthreads();   // zero-init visible before staging

  // stage h(0)=z and x(0) into buffer 0
  for (int item=tid; item<1200; item+=640){
    int t = item >> 3, bb = item & 7;
    float h = ws[OFF_Z + (size_t)(b0+bb)*Hc + t];
    u16 hi = f2us(h); u16 lo = f2us(h - us2f(hi));
    bF[(t>>5)*640 + bb*40 + (t&31)] = hi;
    bF[3200 + (t>>5)*640 + bb*40 + (t&31)] = lo;
  }
  for (int item=tid; item<800; item+=640){
    int bb = item/100, i = item - bb*100;
    bF[XB + (i>>5)*640 + bb*40 + (i&31)] = f2us(ws[OFF_WX + (size_t)(b0+bb)*KWc + i]);
  }

  int bb0 = tid/100, i0 = tid - bb0*100;          // item tid (<800 always)
  int it1 = tid + 640;
  int bb1 = it1/100, i1 = it1 - bb1*100;
  bool v1ok = (it1 < 800);

  for (int s=0;s<Kc;s++){
    int rb = s & 1, wb = rb ^ 1;
    float xp0=0.f, xp1=0.f;
    if (s < Kc-1){
      xp0 = ws[OFF_WX + (size_t)(b0+bb0)*KWc + (s+1)*Wc + i0];
      if (v1ok) xp1 = ws[OFF_WX + (size_t)(b0+bb1)*KWc + (s+1)*Wc + i1];
    }
    lds_barrier();
    const u16* xBase = bF + XB + (size_t)rb*2560 + (size_t)n16*40 + (size_t)quad*8;
    const u16* hBase = bF + (size_t)rb*6400 + (size_t)(n16&7)*40 + (size_t)(n16>>3)*3200 + (size_t)quad*8;
    // ---- phase A: wih . x (x cols 8-15 are zero -> lo halves of accR/accZ unaffected) ----
    short8 bx[4];
    #pragma unroll
    for (int c=0;c<4;c++) bx[c] = *(const short8*)(xBase + (size_t)c*640);
    floatx4 accR={0.f,0.f,0.f,0.f}, accZ={0.f,0.f,0.f,0.f};
    floatx4 accNP={0.f,0.f,0.f,0.f}, accNH={0.f,0.f,0.f,0.f};
    #pragma unroll
    for (int c=0;c<4;c++){
      accR  = __builtin_amdgcn_mfma_f32_16x16x32_bf16(wihA[0][c], bx[c], accR, 0,0,0);
      accZ  = __builtin_amdgcn_mfma_f32_16x16x32_bf16(wihA[1][c], bx[c], accZ, 0,0,0);
      accNP = __builtin_amdgcn_mfma_f32_16x16x32_bf16(wihA[2][c], bx[c], accNP, 0,0,0);
    }
    __builtin_amdgcn_sched_barrier(0);
    // ---- phase B: whh . h, hi in cols 0-7, lo in cols 8-15 ----
    short8 bh[5];
    #pragma unroll
    for (int c=0;c<5;c++) bh[c] = *(const short8*)(hBase + (size_t)c*640);
    #pragma unroll
    for (int c=0;c<5;c++){
      accR  = __builtin_amdgcn_mfma_f32_16x16x32_bf16(whhA[0][c], bh[c], accR, 0,0,0);
      accZ  = __builtin_amdgcn_mfma_f32_16x16x32_bf16(whhA[1][c], bh[c], accZ, 0,0,0);
      accNH = __builtin_amdgcn_mfma_f32_16x16x32_bf16(whhA[2][c], bh[c], accNH, 0,0,0);
    }
    #pragma unroll
    for (int r=0;r<4;r++){
      accR[r]  += __shfl_xor(accR[r], 8);
      accZ[r]  += __shfl_xor(accZ[r], 8);
      accNH[r] += __shfl_xor(accNH[r], 8);   // accNP lo-half is zero: no combine
    }
    if (n16 < 8){
      float hout[4];
      #pragma unroll
      for (int r=0;r<4;r++){
        float a_r = accR[r] + brz_r[r];
        float a_z = accZ[r] + brz_z[r];
        float rr = 1.f/(1.f+__expf(-a_r));
        float zz = 1.f/(1.f+__expf(-a_z));
        float nx = (accNP[r] + bnp_[r]) + rr*(accNH[r] + bnh_[r]);
        nx = fminf(fmaxf(nx,-15.f),15.f);
        float e2 = __expf(2.f*nx);
        float n = (e2-1.f)/(e2+1.f);
        float h = (1.f-zz)*n + zz*hprev[r];
        hprev[r] = h; hout[r] = h;
      }
      u16 h0=f2us(hout[0]), h1=f2us(hout[1]), h2=f2us(hout[2]), h3=f2us(hout[3]);
      u16 l0=f2us(hout[0]-us2f(h0)), l1=f2us(hout[1]-us2f(h1));
      u16 l2=f2us(hout[2]-us2f(h2)), l3=f2us(hout[3]-us2f(h3));
      u64 hiP = (u64)h0 | ((u64)h1<<16) | ((u64)h2<<32) | ((u64)h3<<48);
      u64 loP = (u64)l0 | ((u64)l1<<16) | ((u64)l2<<32) | ((u64)l3<<48);
      u32 wbase = (u32)wb*6400u + (u32)(t0>>5)*640u + (u32)n16*40u + (u32)(t0&31);
      *(u64*)(bF + wbase)        = hiP;   // rows >=150 garbage OK (A k-guard zeros)
      *(u64*)(bF + wbase + 3200) = loP;
      if (s == Kc-1){
        #pragma unroll
        for (int r=0;r<4;r++){
          int t = t0 + r;
          if (t < Hc) out[((size_t)(b0+n16)*Kc + kk)*Hc + t] = hout[r];
        }
      }
    }
    if (s < Kc-1){
      bF[XB + wb*2560 + (i0>>5)*640 + bb0*40 + (i0&31)] = f2us(xp0);
      if (v1ok) bF[XB + wb*2560 + (i1>>5)*640 + bb1*40 + (i1&31)] = f2us(xp1);
    }
  }
}

extern "C" void kernel_launch(void* const* d_in, const int* in_sizes, int n_in,
                              void* d_out, int out_size, void* d_ws, size_t ws_size,
                              hipStream_t stream){
  const float* x        = (const float*)d_in[0];
  const float* y        = (const float*)d_in[1];
  const float* z_noise  = (const float*)d_in[2];
  const float* lin_w    = (const float*)d_in[3];
  const float* lin_b    = (const float*)d_in[4];
  const float* a        = (const float*)d_in[5];
  const float* bias     = (const float*)d_in[6];
  const float* gl_wih   = (const float*)d_in[7];
  const float* gl_whh   = (const float*)d_in[8];
  const float* gl_bih   = (const float*)d_in[9];
  const float* gl_bhh   = (const float*)d_in[10];
  const float* mu_w     = (const float*)d_in[11];
  const float* mu_b     = (const float*)d_in[12];
  const float* std_w    = (const float*)d_in[13];
  const float* std_b    = (const float*)d_in[14];
  const float* net_wih  = (const float*)d_in[15];
  const float* net_whh  = (const float*)d_in[16];
  const float* net_bih  = (const float*)d_in[17];
  const float* net_bhh  = (const float*)d_in[18];
  float* ws = (float*)d_ws;
  float* out = (float*)d_out;

  wx_kernel<<<(Bc*KWc+255)/256, 256, 0, stream>>>(x, lin_w, lin_b, ws);
  attn_kernel<<<Bc*Kc, 256, 0, stream>>>(y, a, bias, ws);
  glproj_kernel<<<(Kc*Bc*H3c+255)/256, 256, 0, stream>>>(gl_wih, gl_bih, ws);
  glgru4_kernel<<<4, 640, 0, stream>>>(gl_whh, gl_bhh, ws);
  z_kernel<<<(Bc*Hc+255)/256, 256, 0, stream>>>(z_noise, mu_w, mu_b, std_w, std_b, ws);
  causes3_kernel<<<Kc*4, 640, 0, stream>>>(net_wih, net_whh, net_bih, net_bhh, ws, out);
}

// Round 11
// 488.727 us; speedup vs baseline: 1.1351x; 1.1351x over previous
//
#include <hip/hip_runtime.h>

#define Bc 32
#define Kc 64
#define Wc 100
#define Hc 150
#define H3c 450
#define KWc 6400
#define ALPHAc 0.2f
#define THRESc 0.0002f

typedef unsigned int u32;
typedef unsigned short u16;
typedef __attribute__((ext_vector_type(8))) short short8;   // 8 bf16
typedef __attribute__((ext_vector_type(4))) float floatx4;  // 4 f32 acc

// ---- ws layout (float offsets), 4.55 MB ----
#define OFF_WX      0u          // 204800  Wx (B,K,W) fp32
#define OFF_CS      204800u     // 2048    causesum (B,K)
#define OFF_GX      206848u     // 921600  gl proj (s,b,g)
#define OFF_HT      1128448u    // 4800    h_t (B,H)
#define OFF_Z       1133248u    // 4800    z (B,H)

__device__ __forceinline__ float us2f(u16 u){ u32 x=((u32)u)<<16; return __uint_as_float(x); }
__device__ __forceinline__ u16 f2us(float f){
  u32 x = __float_as_uint(f);
  u32 r = (x + 0x7fffu + ((x>>16)&1u)) >> 16;   // RNE bf16
  return (u16)r;
}

// LDS-only barrier: skips the vmcnt(0) drain __syncthreads would emit; global
// loads issued before it stay in flight (consumed via register deps).
__device__ __forceinline__ void lds_barrier(){
  __builtin_amdgcn_sched_barrier(0);
  asm volatile("s_waitcnt lgkmcnt(0)" ::: "memory");
  __builtin_amdgcn_s_barrier();
  __builtin_amdgcn_sched_barrier(0);
}

// ---------- Wx = x @ lin_w.T + lin_b ----------
__global__ void wx_kernel(const float* __restrict__ x, const float* __restrict__ lin_w,
                          const float* __restrict__ lin_b, float* __restrict__ ws){
  int o = blockIdx.x*256 + threadIdx.x;
  if (o >= Bc*KWc) return;
  int i = o % Wc;
  int bk = o / Wc;
  const float4* xr = (const float4*)(x + bk*Wc);
  const float4* wr = (const float4*)(lin_w + i*Wc);
  float acc = lin_b[i];
  #pragma unroll
  for (int j=0;j<25;j++){
    float4 xv = xr[j], wv = wr[j];
    acc += xv.x*wv.x + xv.y*wv.y + xv.z*wv.z + xv.w*wv.w;
  }
  ws[OFF_WX + o] = acc;
}

// ---------- attention softmax + thresholded sum (float4, __expf, log-threshold) ----------
__global__ void attn_kernel(const float* __restrict__ y, const float* __restrict__ a,
                            const float* __restrict__ bias, float* __restrict__ ws){
  __shared__ __align__(16) float e_l[KWc];
  __shared__ float red[4];
  int row = blockIdx.x;          // b*64 + k
  int b = row >> 6, k = row & 63;
  int tid = threadIdx.x;
  float a0 = a[0], a1 = a[1];
  float yv = y[row];
  const float4* v4  = (const float4*)(ws + OFF_WX + (size_t)b*KWc);
  const float4* br4 = (const float4*)(bias + (size_t)k*KWc);
  float4* e4 = (float4*)e_l;
  float ay = a0*yv;
  float m = -3.4e38f;
  for (int j=tid; j<KWc/4; j+=256){
    float4 vv = v4[j], bb = br4[j];
    float4 e;
    e.x = ay + a1*vv.x + bb.x; e.x = (e.x>=0.f)?e.x:ALPHAc*e.x;
    e.y = ay + a1*vv.y + bb.y; e.y = (e.y>=0.f)?e.y:ALPHAc*e.y;
    e.z = ay + a1*vv.z + bb.z; e.z = (e.z>=0.f)?e.z:ALPHAc*e.z;
    e.w = ay + a1*vv.w + bb.w; e.w = (e.w>=0.f)?e.w:ALPHAc*e.w;
    e4[j] = e;
    m = fmaxf(m, fmaxf(fmaxf(e.x,e.y), fmaxf(e.z,e.w)));
  }
  for (int o=32;o;o>>=1) m = fmaxf(m, __shfl_down(m, o));
  if ((tid&63)==0) red[tid>>6] = m;
  __syncthreads();
  m = fmaxf(fmaxf(red[0],red[1]), fmaxf(red[2],red[3]));
  __syncthreads();
  float ssum = 0.f;
  for (int j=tid; j<KWc/4; j+=256){
    float4 e = e4[j];
    ssum += __expf(e.x-m) + __expf(e.y-m) + __expf(e.z-m) + __expf(e.w-m);
  }
  for (int o=32;o;o>>=1) ssum += __shfl_down(ssum, o);
  if ((tid&63)==0) red[tid>>6] = ssum;
  __syncthreads();
  float s = red[0]+red[1]+red[2]+red[3];
  float thr = m + logf(THRESc * s);
  float cs = 0.f;
  for (int j=tid; j<KWc/4; j+=256){
    float4 e = e4[j];
    float4 vv = v4[j];
    if (e.x >= thr) cs += vv.x;
    if (e.y >= thr) cs += vv.y;
    if (e.z >= thr) cs += vv.z;
    if (e.w >= thr) cs += vv.w;
  }
  for (int o=32;o;o>>=1) cs += __shfl_down(cs, o);
  if ((tid&63)==0) red[tid>>6] = cs;
  __syncthreads();
  if (tid==0) ws[OFF_CS + row] = red[0]+red[1]+red[2]+red[3];
}

// ---------- gl input projection ----------
__global__ void glproj_kernel(const float* __restrict__ gl_wih, const float* __restrict__ gl_bih,
                              float* __restrict__ ws){
  int o = blockIdx.x*256 + threadIdx.x;
  if (o >= Kc*Bc*H3c) return;
  int g = o % H3c;
  int t = o / H3c;               // s*32 + b
  int b = t & 31, s = t >> 5;
  float cs = ws[OFF_CS + b*Kc + s];
  const float4* xr = (const float4*)(ws + OFF_WX + b*KWc + s*Wc);
  const float4* wr = (const float4*)(gl_wih + g*Wc);
  float acc = gl_bih[g];
  #pragma unroll
  for (int j=0;j<25;j++){
    float4 wv = wr[j], xv = xr[j];
    acc += (xv.x+cs)*wv.x + (xv.y+cs)*wv.y + (xv.z+cs)*wv.z + (xv.w+cs)*wv.w;
  }
  ws[OFF_GX + o] = acc;
}

// ---------- gl recurrent GRU v13: round-8 skeleton + hi/lo packed B-cols ----------
// h_hi in cols 0-7 (batch bl), h_lo in cols 8-15 (bl+8): whh chunks 10 -> 5.
// One shfl_xor(8)+add merges halves; lanes 0-7 hold totals (existing n16<8 dump).
__global__ void __launch_bounds__(512,1) glgru4_kernel(
    const float* __restrict__ gl_whh, const float* __restrict__ gl_bhh,
    float* __restrict__ ws){
  __shared__ __align__(16) u16 bF[5*16*40];    // 5 chunks x [col16][k-row stride 40]
  __shared__ float g_l[480*10];                // gate rows x 8 batches, stride 10
  int b0 = blockIdx.x*8;
  int tid = threadIdx.x;
  int w = tid >> 6, lane = tid & 63, quad = lane >> 4, n16 = lane & 15;

  // ---- resident A-fragments (float2 loads) ----
  short8 whhA[4][5];
  #pragma unroll
  for (int ti=0; ti<4; ti++){
    int tile = w*4 + ti;                 // 0..31 (30,31 dummy)
    int sec = tile/10;
    int sr = (tile - sec*10)*16 + n16;
    bool rowok = (tile < 30) && (sr < Hc);
    int grow = (sec<3 ? sec : 2)*Hc + sr;
    const float* wr = gl_whh + (size_t)grow*Hc;
    #pragma unroll
    for (int c=0;c<5;c++){
      union { short8 v; u16 u[8]; } t8;
      #pragma unroll
      for (int j2=0;j2<4;j2++){
        int kk2 = c*32 + quad*8 + j2*2;
        float2 wv = (rowok && (kk2+1) < Hc) ? *(const float2*)(wr + kk2) : make_float2(0.f,0.f);
        t8.u[j2*2]   = f2us(wv.x);
        t8.u[j2*2+1] = f2us(wv.y);
      }
      whhA[ti][c] = t8.v;
    }
  }
  for (int i=tid; i<5*16*40/2; i+=512) ((u32*)bF)[i] = 0u;   // h(0)=0

  float hst[3] = {0.f,0.f,0.f};
  float bh_r[3], bh_z[3], bh_n[3];
  int tT[3], tBL[3];
  #pragma unroll
  for (int q=0;q<3;q++){
    int task = tid + q*512;
    if (task < 1200){
      int bl = task/150, t = task - bl*150;
      tT[q] = t; tBL[q] = bl;
      bh_r[q] = gl_bhh[t];
      bh_z[q] = gl_bhh[Hc+t];
      bh_n[q] = gl_bhh[2*Hc+t];
    } else { tT[q] = 0; tBL[q] = -1; }
  }

  for (int s=0;s<Kc;s++){
    lds_barrier();   // bF ready
    // gx prefetch (after barrier -> hidden under MFMA phase)
    float gxr[3], gxz[3], gxn[3];
    const float* gxb = ws + OFF_GX + (size_t)(s*Bc)*H3c;
    #pragma unroll
    for (int q=0;q<3;q++){
      if (tBL[q] >= 0){
        const float* gp = gxb + (size_t)(b0+tBL[q])*H3c;
        int t = tT[q];
        gxr[q] = gp[t]; gxz[q] = gp[Hc+t]; gxn[q] = gp[2*Hc+t];
      }
    }
    // MFMA stage: 5 packed chunks, single burst
    const u16* bBase = bF + (size_t)n16*40 + (size_t)quad*8;
    short8 bh[5];
    #pragma unroll
    for (int c=0;c<5;c++) bh[c] = *(const short8*)(bBase + (size_t)c*640);
    floatx4 acc[4] = {{0.f,0.f,0.f,0.f},{0.f,0.f,0.f,0.f},{0.f,0.f,0.f,0.f},{0.f,0.f,0.f,0.f}};
    #pragma unroll
    for (int c=0;c<5;c++){
      #pragma unroll
      for (int ti=0;ti<4;ti++)
        acc[ti] = __builtin_amdgcn_mfma_f32_16x16x32_bf16(whhA[ti][c], bh[c], acc[ti], 0,0,0);
    }
    // merge hi (lanes 0-7) + lo (lanes 8-15) halves
    #pragma unroll
    for (int ti=0;ti<4;ti++){
      #pragma unroll
      for (int r=0;r<4;r++) acc[ti][r] += __shfl_xor(acc[ti][r], 8);
    }
    // C -> LDS (col=lane&15, row=quad*4+reg); lanes 0-7 hold merged totals
    if (n16 < 8){
      #pragma unroll
      for (int ti=0;ti<4;ti++){
        int tile = w*4 + ti;
        if (tile < 30){
          int row0 = tile*16 + quad*4;
          float* gp = g_l + row0*10 + n16;
          #pragma unroll
          for (int r=0;r<4;r++) gp[r*10] = acc[ti][r];
        }
      }
    }
    lds_barrier();   // gates ready; bF MFMA reads done
    float grv[3], gzv[3], gnv[3];
    #pragma unroll
    for (int q=0;q<3;q++){
      if (tBL[q] >= 0){
        int t = tT[q], bl = tBL[q];
        grv[q] = g_l[t*10+bl];
        gzv[q] = g_l[(160+t)*10+bl];
        gnv[q] = g_l[(320+t)*10+bl];
      }
    }
    #pragma unroll
    for (int q=0;q<3;q++){
      if (tBL[q] >= 0){
        int t = tT[q], bl = tBL[q];
        float a_r = gxr[q] + grv[q] + bh_r[q];
        float a_z = gxz[q] + gzv[q] + bh_z[q];
        float r  = 1.f/(1.f+__expf(-a_r));
        float zz = 1.f/(1.f+__expf(-a_z));
        float nx = gxn[q] + r*(gnv[q] + bh_n[q]);
        nx = fminf(fmaxf(nx,-15.f),15.f);
        float e2 = __expf(2.f*nx);
        float n = (e2-1.f)/(e2+1.f);
        float h = (1.f-zz)*n + zz*hst[q];
        hst[q] = h;
        u16 hi = f2us(h); float hif = us2f(hi); u16 lo = f2us(h - hif);
        bF[(t>>5)*640 + bl*40 + (t&31)] = hi;           // hi -> col bl
        bF[(t>>5)*640 + (bl+8)*40 + (t&31)] = lo;       // lo -> col bl+8
      }
    }
  }
  #pragma unroll
  for (int q=0;q<3;q++){
    if (tBL[q] >= 0)
      ws[OFF_HT + (size_t)(b0+tBL[q])*Hc + tT[q]] = hst[q];
  }
}

// ---------- z = mu + sigma * z_noise ----------
__global__ void z_kernel(const float* __restrict__ z_noise, const float* __restrict__ mu_w,
                         const float* __restrict__ mu_b, const float* __restrict__ std_w,
                         const float* __restrict__ std_b, float* __restrict__ ws){
  int o = blockIdx.x*256 + threadIdx.x;
  if (o >= Bc*Hc) return;
  int t = o % Hc, b = o / Hc;
  const float* h = ws + OFF_HT + b*Hc;
  const float2* mwr = (const float2*)(mu_w + t*Hc);
  const float2* swr = (const float2*)(std_w + t*Hc);
  float mu = mu_b[t], lv = std_b[t];
  for (int j=0;j<Hc/2;j++){
    float2 mw = mwr[j], sw = swr[j];
    float h0 = h[2*j], h1 = h[2*j+1];
    mu += h0*mw.x + h1*mw.y;
    lv += h0*sw.x + h1*sw.y;
  }
  float sg = expf(0.5f*lv);
  ws[OFF_Z + o] = mu + sg*z_noise[o];
}

// ---------- causes v13: round-7 skeleton + hi/lo packed B-cols (whh chunks 10->5) ----------
// h chunks 0-4 (hi cols 0-7, lo cols 8-15); x chunks 5-8 (cols 0-7, 8-15 zero).
// After phase B one shfl_xor(8)+add merges halves; isN g_np dump (phase A, cols 0-7
// complete) needs no merge. MFMA/block-step 448 -> 288.
__global__ void __launch_bounds__(512,1) causes3_kernel(
    const float* __restrict__ net_wih, const float* __restrict__ net_whh,
    const float* __restrict__ net_bih, const float* __restrict__ net_bhh,
    const float* __restrict__ ws, float* __restrict__ out){
  __shared__ __align__(16) u16 bF[9*16*40];    // h: 5 chunks packed; x: 4 chunks
  __shared__ float g_rz[320*10];
  __shared__ float g_nh[160*10];
  __shared__ float g_np[160*10];
  int kk = blockIdx.x & 63, bg = blockIdx.x >> 6, b0 = bg*8;
  int tid = threadIdx.x;
  int w = tid >> 6, lane = tid & 63, quad = lane >> 4, n16 = lane & 15;
  const float* whhk = net_whh + (size_t)kk*H3c*Hc;
  const float* wihk = net_wih + (size_t)kk*H3c*Wc;
  const float* bihk = net_bih + kk*H3c;
  const float* bhhk = net_bhh + kk*H3c;

  short8 whhA[4][5], wihA[4][4];
  #pragma unroll
  for (int ti=0; ti<4; ti++){
    int tile = w*4 + ti;
    int sec = tile/10;
    int sr = (tile - sec*10)*16 + n16;
    bool rowok = (tile < 30) && (sr < Hc);
    int grow = (sec<3 ? sec : 2)*Hc + sr;
    #pragma unroll
    for (int c=0;c<5;c++){
      union { short8 v; u16 u[8]; } t8;
      #pragma unroll
      for (int j=0;j<8;j++){
        int k = c*32 + quad*8 + j;
        float v = (rowok && k < Hc) ? whhk[(size_t)grow*Hc + k] : 0.f;
        t8.u[j] = f2us(v);
      }
      whhA[ti][c] = t8.v;
    }
    #pragma unroll
    for (int c=0;c<4;c++){
      union { short8 v; u16 u[8]; } t8;
      #pragma unroll
      for (int j=0;j<8;j++){
        int k = c*32 + quad*8 + j;
        float v = (rowok && k < Wc) ? wihk[(size_t)grow*Wc + k] : 0.f;
        t8.u[j] = f2us(v);
      }
      wihA[ti][c] = t8.v;
    }
  }

  for (int i=tid; i<9*16*40/2; i+=512) ((u32*)bF)[i] = 0u;

  float hst[3] = {0.f,0.f,0.f};
  float brz_r[3], brz_z[3], bnh_[3], bnp_[3];
  #pragma unroll
  for (int q=0;q<3;q++){
    int task = tid + q*512;
    if (task < 1200){
      int t = task >> 3, bb = task & 7;
      float h = ws[OFF_Z + (b0+bb)*Hc + t];
      hst[q] = h;
      brz_r[q] = bhhk[t]      + bihk[t];
      brz_z[q] = bhhk[Hc+t]   + bihk[Hc+t];
      bnh_[q]  = bhhk[2*Hc+t];
      bnp_[q]  = bihk[2*Hc+t];
      u16 hi = f2us(h); float hif = us2f(hi); u16 lo = f2us(h - hif);
      bF[(t>>5)*640 + bb*40 + (t&31)] = hi;
      bF[(t>>5)*640 + (bb+8)*40 + (t&31)] = lo;
    }
  }
  for (int it=tid; it<800; it+=512){
    int bb = it/100, i = it - bb*100;
    float xv = ws[OFF_WX + (b0+bb)*KWc + i];
    bF[(5+(i>>5))*640 + bb*40 + (i&31)] = f2us(xv);
  }

  // x-staging indices: item0 = tid (<800 always), item1 = tid+512 (<800 iff tid<288)
  int bb0 = tid/100, i0 = tid - bb0*100;
  int it1 = tid + 512;
  int bb1 = it1/100, i1 = it1 - bb1*100;
  bool v1ok = (it1 < 800);

  const bool isN = (w >= 5);
  for (int s=0;s<Kc;s++){
    // hoisted x loads for next step (in flight across the lgkm-only barrier)
    float xp0 = 0.f, xp1 = 0.f;
    if (s < Kc-1){
      xp0 = ws[OFF_WX + (size_t)(b0+bb0)*KWc + (s+1)*Wc + i0];
      if (v1ok) xp1 = ws[OFF_WX + (size_t)(b0+bb1)*KWc + (s+1)*Wc + i1];
    }
    lds_barrier();   // h+x staging ready
    const u16* bBase = bF + (size_t)n16*40 + (size_t)quad*8;
    // single burst: x chunks + packed h chunks (36 B-regs live, fits easily)
    short8 bx[4];
    #pragma unroll
    for (int c=0;c<4;c++) bx[c] = *(const short8*)(bBase + (size_t)(5+c)*640);
    short8 bh[5];
    #pragma unroll
    for (int c=0;c<5;c++) bh[c] = *(const short8*)(bBase + (size_t)c*640);
    // ---- phase A: wih . x ----
    floatx4 acc[4] = {{0.f,0.f,0.f,0.f},{0.f,0.f,0.f,0.f},{0.f,0.f,0.f,0.f},{0.f,0.f,0.f,0.f}};
    #pragma unroll
    for (int ca=0;ca<4;ca++){
      #pragma unroll
      for (int ti=0;ti<4;ti++)
        acc[ti] = __builtin_amdgcn_mfma_f32_16x16x32_bf16(wihA[ti][ca], bx[ca], acc[ti], 0,0,0);
    }
    // n-waves: dump P-part (cols 0-7 complete: x cols 8-15 are zero), reset acc
    if (isN){
      if (n16 < 8){
        #pragma unroll
        for (int ti=0;ti<4;ti++){
          int tile = w*4 + ti;
          if (tile < 30){
            int srb = (tile - 20)*16 + quad*4;
            float* gq = g_np + srb*10 + n16;
            #pragma unroll
            for (int r=0;r<4;r++) gq[r*10] = acc[ti][r];
          }
        }
      }
      #pragma unroll
      for (int ti=0;ti<4;ti++) acc[ti] = (floatx4){0.f,0.f,0.f,0.f};
    }
    // ---- phase B: whh . h, 5 packed chunks ----
    #pragma unroll
    for (int c=0;c<5;c++){
      #pragma unroll
      for (int ti=0;ti<4;ti++)
        acc[ti] = __builtin_amdgcn_mfma_f32_16x16x32_bf16(whhA[ti][c], bh[c], acc[ti], 0,0,0);
    }
    // merge hi/lo halves (r/z waves: phase A lives only in cols 0-7, lane b+8 adds 0)
    #pragma unroll
    for (int ti=0;ti<4;ti++){
      #pragma unroll
      for (int r=0;r<4;r++) acc[ti][r] += __shfl_xor(acc[ti][r], 8);
    }
    if (n16 < 8){
      #pragma unroll
      for (int ti=0;ti<4;ti++){
        int tile = w*4 + ti;
        if (tile < 30){
          int sec = tile/10;
          int srb = (tile - sec*10)*16 + quad*4;
          if (sec < 2){
            float* gp = g_rz + (sec*160 + srb)*10 + n16;
            #pragma unroll
            for (int r=0;r<4;r++) gp[r*10] = acc[ti][r];
          } else {
            float* gh = g_nh + srb*10 + n16;
            #pragma unroll
            for (int r=0;r<4;r++) gh[r*10] = acc[ti][r];
          }
        }
      }
    }
    lds_barrier();   // gates ready; bF MFMA reads done
    #pragma unroll
    for (int q=0;q<3;q++){
      int task = tid + q*512;
      if (task < 1200){
        int t = task >> 3, bb = task & 7;
        float a_r = g_rz[t*10+bb] + brz_r[q];
        float a_z = g_rz[(160+t)*10+bb] + brz_z[q];
        float r  = 1.f/(1.f+__expf(-a_r));
        float zz = 1.f/(1.f+__expf(-a_z));
        float nx = (g_np[t*10+bb] + bnp_[q]) + r*(g_nh[t*10+bb] + bnh_[q]);
        nx = fminf(fmaxf(nx,-15.f),15.f);
        float e2 = __expf(2.f*nx);
        float n = (e2-1.f)/(e2+1.f);
        float h = (1.f-zz)*n + zz*hst[q];
        hst[q] = h;
        u16 hi = f2us(h); float hif = us2f(hi); u16 lo = f2us(h - hif);
        bF[(t>>5)*640 + bb*40 + (t&31)] = hi;           // hi -> col bb
        bF[(t>>5)*640 + (bb+8)*40 + (t&31)] = lo;       // lo -> col bb+8
      }
    }
    if (s < Kc-1){
      bF[(5+(i0>>5))*640 + bb0*40 + (i0&31)] = f2us(xp0);
      if (v1ok) bF[(5+(i1>>5))*640 + bb1*40 + (i1&31)] = f2us(xp1);
    }
  }
  #pragma unroll
  for (int q=0;q<3;q++){
    int task = tid + q*512;
    if (task < 1200){
      int t = task >> 3, bb = task & 7;
      out[((size_t)(b0+bb)*Kc + kk)*Hc + t] = hst[q];
    }
  }
}

extern "C" void kernel_launch(void* const* d_in, const int* in_sizes, int n_in,
                              void* d_out, int out_size, void* d_ws, size_t ws_size,
                              hipStream_t stream){
  const float* x        = (const float*)d_in[0];
  const float* y        = (const float*)d_in[1];
  const float* z_noise  = (const float*)d_in[2];
  const float* lin_w    = (const float*)d_in[3];
  const float* lin_b    = (const float*)d_in[4];
  const float* a        = (const float*)d_in[5];
  const float* bias     = (const float*)d_in[6];
  const float* gl_wih   = (const float*)d_in[7];
  const float* gl_whh   = (const float*)d_in[8];
  const float* gl_bih   = (const float*)d_in[9];
  const float* gl_bhh   = (const float*)d_in[10];
  const float* mu_w     = (const float*)d_in[11];
  const float* mu_b     = (const float*)d_in[12];
  const float* std_w    = (const float*)d_in[13];
  const float* std_b    = (const float*)d_in[14];
  const float* net_wih  = (const float*)d_in[15];
  const float* net_whh  = (const float*)d_in[16];
  const float* net_bih  = (const float*)d_in[17];
  const float* net_bhh  = (const float*)d_in[18];
  float* ws = (float*)d_ws;
  float* out = (float*)d_out;

  wx_kernel<<<(Bc*KWc+255)/256, 256, 0, stream>>>(x, lin_w, lin_b, ws);
  attn_kernel<<<Bc*Kc, 256, 0, stream>>>(y, a, bias, ws);
  glproj_kernel<<<(Kc*Bc*H3c+255)/256, 256, 0, stream>>>(gl_wih, gl_bih, ws);
  glgru4_kernel<<<4, 512, 0, stream>>>(gl_whh, gl_bhh, ws);
  z_kernel<<<(Bc*Hc+255)/256, 256, 0, stream>>>(z_noise, mu_w, mu_b, std_w, std_b, ws);
  causes3_kernel<<<Kc*4, 512, 0, stream>>>(net_wih, net_whh, net_bih, net_bhh, ws, out);
}

// Round 12
// 483.752 us; speedup vs baseline: 1.1468x; 1.0103x over previous
//
#include <hip/hip_runtime.h>

#define Bc 32
#define Kc 64
#define Wc 100
#define Hc 150
#define H3c 450
#define KWc 6400
#define ALPHAc 0.2f
#define THRESc 0.0002f

typedef unsigned int u32;
typedef unsigned short u16;
typedef __attribute__((ext_vector_type(8))) short short8;   // 8 bf16
typedef __attribute__((ext_vector_type(4))) float floatx4;  // 4 f32 acc

// ---- ws layout (float offsets), 4.55 MB ----
#define OFF_WX      0u          // 204800  Wx (B,K,W) fp32
#define OFF_CS      204800u     // 2048    causesum (B,K)
#define OFF_GX      206848u     // 921600  gl proj (s,b,g)
#define OFF_HT      1128448u    // 4800    h_t (B,H)
#define OFF_Z       1133248u    // 4800    z (B,H)

__device__ __forceinline__ float us2f(u16 u){ u32 x=((u32)u)<<16; return __uint_as_float(x); }
__device__ __forceinline__ u16 f2us(float f){
  u32 x = __float_as_uint(f);
  u32 r = (x + 0x7fffu + ((x>>16)&1u)) >> 16;   // RNE bf16
  return (u16)r;
}

// LDS-only barrier: skips the vmcnt(0) drain __syncthreads would emit; global
// loads issued before it stay in flight (consumed via register deps).
__device__ __forceinline__ void lds_barrier(){
  __builtin_amdgcn_sched_barrier(0);
  asm volatile("s_waitcnt lgkmcnt(0)" ::: "memory");
  __builtin_amdgcn_s_barrier();
  __builtin_amdgcn_sched_barrier(0);
}

// ---------- Wx = x @ lin_w.T + lin_b ----------
__global__ void wx_kernel(const float* __restrict__ x, const float* __restrict__ lin_w,
                          const float* __restrict__ lin_b, float* __restrict__ ws){
  int o = blockIdx.x*256 + threadIdx.x;
  if (o >= Bc*KWc) return;
  int i = o % Wc;
  int bk = o / Wc;
  const float4* xr = (const float4*)(x + bk*Wc);
  const float4* wr = (const float4*)(lin_w + i*Wc);
  float acc = lin_b[i];
  #pragma unroll
  for (int j=0;j<25;j++){
    float4 xv = xr[j], wv = wr[j];
    acc += xv.x*wv.x + xv.y*wv.y + xv.z*wv.z + xv.w*wv.w;
  }
  ws[OFF_WX + o] = acc;
}

// ---------- attention softmax + thresholded sum (float4, __expf, log-threshold) ----------
__global__ void attn_kernel(const float* __restrict__ y, const float* __restrict__ a,
                            const float* __restrict__ bias, float* __restrict__ ws){
  __shared__ __align__(16) float e_l[KWc];
  __shared__ float red[4];
  int row = blockIdx.x;          // b*64 + k
  int b = row >> 6, k = row & 63;
  int tid = threadIdx.x;
  float a0 = a[0], a1 = a[1];
  float yv = y[row];
  const float4* v4  = (const float4*)(ws + OFF_WX + (size_t)b*KWc);
  const float4* br4 = (const float4*)(bias + (size_t)k*KWc);
  float4* e4 = (float4*)e_l;
  float ay = a0*yv;
  float m = -3.4e38f;
  for (int j=tid; j<KWc/4; j+=256){
    float4 vv = v4[j], bb = br4[j];
    float4 e;
    e.x = ay + a1*vv.x + bb.x; e.x = (e.x>=0.f)?e.x:ALPHAc*e.x;
    e.y = ay + a1*vv.y + bb.y; e.y = (e.y>=0.f)?e.y:ALPHAc*e.y;
    e.z = ay + a1*vv.z + bb.z; e.z = (e.z>=0.f)?e.z:ALPHAc*e.z;
    e.w = ay + a1*vv.w + bb.w; e.w = (e.w>=0.f)?e.w:ALPHAc*e.w;
    e4[j] = e;
    m = fmaxf(m, fmaxf(fmaxf(e.x,e.y), fmaxf(e.z,e.w)));
  }
  for (int o=32;o;o>>=1) m = fmaxf(m, __shfl_down(m, o));
  if ((tid&63)==0) red[tid>>6] = m;
  __syncthreads();
  m = fmaxf(fmaxf(red[0],red[1]), fmaxf(red[2],red[3]));
  __syncthreads();
  float ssum = 0.f;
  for (int j=tid; j<KWc/4; j+=256){
    float4 e = e4[j];
    ssum += __expf(e.x-m) + __expf(e.y-m) + __expf(e.z-m) + __expf(e.w-m);
  }
  for (int o=32;o;o>>=1) ssum += __shfl_down(ssum, o);
  if ((tid&63)==0) red[tid>>6] = ssum;
  __syncthreads();
  float s = red[0]+red[1]+red[2]+red[3];
  float thr = m + logf(THRESc * s);
  float cs = 0.f;
  for (int j=tid; j<KWc/4; j+=256){
    float4 e = e4[j];
    float4 vv = v4[j];
    if (e.x >= thr) cs += vv.x;
    if (e.y >= thr) cs += vv.y;
    if (e.z >= thr) cs += vv.z;
    if (e.w >= thr) cs += vv.w;
  }
  for (int o=32;o;o>>=1) cs += __shfl_down(cs, o);
  if ((tid&63)==0) red[tid>>6] = cs;
  __syncthreads();
  if (tid==0) ws[OFF_CS + row] = red[0]+red[1]+red[2]+red[3];
}

// ---------- gl input projection ----------
__global__ void glproj_kernel(const float* __restrict__ gl_wih, const float* __restrict__ gl_bih,
                              float* __restrict__ ws){
  int o = blockIdx.x*256 + threadIdx.x;
  if (o >= Kc*Bc*H3c) return;
  int g = o % H3c;
  int t = o / H3c;               // s*32 + b
  int b = t & 31, s = t >> 5;
  float cs = ws[OFF_CS + b*Kc + s];
  const float4* xr = (const float4*)(ws + OFF_WX + b*KWc + s*Wc);
  const float4* wr = (const float4*)(gl_wih + g*Wc);
  float acc = gl_bih[g];
  #pragma unroll
  for (int j=0;j<25;j++){
    float4 wv = wr[j], xv = xr[j];
    acc += (xv.x+cs)*wv.x + (xv.y+cs)*wv.y + (xv.z+cs)*wv.z + (xv.w+cs)*wv.w;
  }
  ws[OFF_GX + o] = acc;
}

// ---------- gl recurrent GRU v14: VALU matvec, 32 blocks x 1 batch, reg-resident rows ----------
// MFMA was the wrong tool here: batch/block=8 meant 4 blocks (1.5% of GPU) and
// mostly-empty tiles. Now: thread (g,t) owns weight row g*150+t in 75 u32 regs
// (bf16 pairs, loaded once; gl_whh is 270KB -> L2-resident). Per step: 75
// unpack+2FMA iters, h kept in f32 LDS (broadcast reads), 150 finisher lanes
// do gates. h is full f32 now (better precision than the old hi/lo bf16 split).
__global__ void __launch_bounds__(512,1) glgru4_kernel(
    const float* __restrict__ gl_whh, const float* __restrict__ gl_bhh,
    float* __restrict__ ws){
  __shared__ __align__(16) float hbuf[2][152];
  __shared__ float dotb[3*152];
  int b = blockIdx.x;            // one batch per block
  int tid = threadIdx.x;
  bool dotter = (tid < 450);
  int g = dotter ? tid/150 : 0;
  int t = dotter ? (tid - g*150) : 0;

  // prologue: pack this thread's weight row into 75 u32 registers
  u32 wreg[75];
  {
    const float* wr = gl_whh + (size_t)(g*Hc + t)*Hc;   // row g*150+t
    #pragma unroll
    for (int k2=0;k2<75;k2++){
      float2 wv = dotter ? *(const float2*)(wr + 2*k2) : make_float2(0.f,0.f);
      wreg[k2] = (u32)f2us(wv.x) | ((u32)f2us(wv.y) << 16);
    }
  }
  if (tid < 152){ hbuf[0][tid] = 0.f; hbuf[1][tid] = 0.f; }

  float bh_r=0.f, bh_z=0.f, bh_n=0.f, hreg=0.f;
  if (tid < Hc){
    bh_r = gl_bhh[tid]; bh_z = gl_bhh[Hc+tid]; bh_n = gl_bhh[2*Hc+tid];
  }
  __syncthreads();

  for (int s=0;s<Kc;s++){
    int rb = s & 1;
    // finisher gx loads: issued first, consumed after the dot phase (deps hide them)
    float gxr=0.f, gxz=0.f, gxn=0.f;
    if (tid < Hc){
      const float* gp = ws + OFF_GX + (size_t)(s*Bc + b)*H3c;
      gxr = gp[tid]; gxz = gp[Hc+tid]; gxn = gp[2*Hc+tid];
    }
    if (dotter){
      const float* hb = hbuf[rb];
      float a0=0.f, a1=0.f, a2=0.f;
      #pragma unroll
      for (int k2=0;k2<75;k2+=3){
        u32 u0 = wreg[k2], u1 = wreg[k2+1], u2 = wreg[k2+2];
        float2 h0 = *(const float2*)(hb + 2*k2);
        float2 h1 = *(const float2*)(hb + 2*k2+2);
        float2 h2 = *(const float2*)(hb + 2*k2+4);
        a0 += __uint_as_float(u0<<16)*h0.x + __uint_as_float(u0&0xffff0000u)*h0.y;
        a1 += __uint_as_float(u1<<16)*h1.x + __uint_as_float(u1&0xffff0000u)*h1.y;
        a2 += __uint_as_float(u2<<16)*h2.x + __uint_as_float(u2&0xffff0000u)*h2.y;
      }
      dotb[g*152 + t] = a0 + a1 + a2;
    }
    lds_barrier();   // dots ready
    if (tid < Hc){
      float a_r = gxr + dotb[tid]       + bh_r;
      float a_z = gxz + dotb[152+tid]   + bh_z;
      float dn  =       dotb[304+tid]   + bh_n;
      float rr = 1.f/(1.f+__expf(-a_r));
      float zz = 1.f/(1.f+__expf(-a_z));
      float nx = gxn + rr*dn;
      nx = fminf(fmaxf(nx,-15.f),15.f);
      float e2 = __expf(2.f*nx);
      float n = (e2-1.f)/(e2+1.f);
      float h = (1.f-zz)*n + zz*hreg;
      hreg = h;
      hbuf[rb^1][tid] = h;
    }
    lds_barrier();   // h ready; dotb consumed (WAR safe for next step)
  }
  if (tid < Hc) ws[OFF_HT + (size_t)b*Hc + tid] = hreg;
}

// ---------- z = mu + sigma * z_noise ----------
__global__ void z_kernel(const float* __restrict__ z_noise, const float* __restrict__ mu_w,
                         const float* __restrict__ mu_b, const float* __restrict__ std_w,
                         const float* __restrict__ std_b, float* __restrict__ ws){
  int o = blockIdx.x*256 + threadIdx.x;
  if (o >= Bc*Hc) return;
  int t = o % Hc, b = o / Hc;
  const float* h = ws + OFF_HT + b*Hc;
  const float2* mwr = (const float2*)(mu_w + t*Hc);
  const float2* swr = (const float2*)(std_w + t*Hc);
  float mu = mu_b[t], lv = std_b[t];
  for (int j=0;j<Hc/2;j++){
    float2 mw = mwr[j], sw = swr[j];
    float h0 = h[2*j], h1 = h[2*j+1];
    mu += h0*mw.x + h1*mw.y;
    lv += h0*sw.x + h1*sw.y;
  }
  float sg = expf(0.5f*lv);
  ws[OFF_Z + o] = mu + sg*z_noise[o];
}

// ---------- causes v13 (kept): round-7 skeleton + hi/lo packed B-cols ----------
__global__ void __launch_bounds__(512,1) causes3_kernel(
    const float* __restrict__ net_wih, const float* __restrict__ net_whh,
    const float* __restrict__ net_bih, const float* __restrict__ net_bhh,
    const float* __restrict__ ws, float* __restrict__ out){
  __shared__ __align__(16) u16 bF[9*16*40];    // h: 5 chunks packed; x: 4 chunks
  __shared__ float g_rz[320*10];
  __shared__ float g_nh[160*10];
  __shared__ float g_np[160*10];
  int kk = blockIdx.x & 63, bg = blockIdx.x >> 6, b0 = bg*8;
  int tid = threadIdx.x;
  int w = tid >> 6, lane = tid & 63, quad = lane >> 4, n16 = lane & 15;
  const float* whhk = net_whh + (size_t)kk*H3c*Hc;
  const float* wihk = net_wih + (size_t)kk*H3c*Wc;
  const float* bihk = net_bih + kk*H3c;
  const float* bhhk = net_bhh + kk*H3c;

  short8 whhA[4][5], wihA[4][4];
  #pragma unroll
  for (int ti=0; ti<4; ti++){
    int tile = w*4 + ti;
    int sec = tile/10;
    int sr = (tile - sec*10)*16 + n16;
    bool rowok = (tile < 30) && (sr < Hc);
    int grow = (sec<3 ? sec : 2)*Hc + sr;
    #pragma unroll
    for (int c=0;c<5;c++){
      union { short8 v; u16 u[8]; } t8;
      #pragma unroll
      for (int j=0;j<8;j++){
        int k = c*32 + quad*8 + j;
        float v = (rowok && k < Hc) ? whhk[(size_t)grow*Hc + k] : 0.f;
        t8.u[j] = f2us(v);
      }
      whhA[ti][c] = t8.v;
    }
    #pragma unroll
    for (int c=0;c<4;c++){
      union { short8 v; u16 u[8]; } t8;
      #pragma unroll
      for (int j=0;j<8;j++){
        int k = c*32 + quad*8 + j;
        float v = (rowok && k < Wc) ? wihk[(size_t)grow*Wc + k] : 0.f;
        t8.u[j] = f2us(v);
      }
      wihA[ti][c] = t8.v;
    }
  }

  for (int i=tid; i<9*16*40/2; i+=512) ((u32*)bF)[i] = 0u;

  float hst[3] = {0.f,0.f,0.f};
  float brz_r[3], brz_z[3], bnh_[3], bnp_[3];
  #pragma unroll
  for (int q=0;q<3;q++){
    int task = tid + q*512;
    if (task < 1200){
      int t = task >> 3, bb = task & 7;
      float h = ws[OFF_Z + (b0+bb)*Hc + t];
      hst[q] = h;
      brz_r[q] = bhhk[t]      + bihk[t];
      brz_z[q] = bhhk[Hc+t]   + bihk[Hc+t];
      bnh_[q]  = bhhk[2*Hc+t];
      bnp_[q]  = bihk[2*Hc+t];
      u16 hi = f2us(h); float hif = us2f(hi); u16 lo = f2us(h - hif);
      bF[(t>>5)*640 + bb*40 + (t&31)] = hi;
      bF[(t>>5)*640 + (bb+8)*40 + (t&31)] = lo;
    }
  }
  for (int it=tid; it<800; it+=512){
    int bb = it/100, i = it - bb*100;
    float xv = ws[OFF_WX + (b0+bb)*KWc + i];
    bF[(5+(i>>5))*640 + bb*40 + (i&31)] = f2us(xv);
  }

  int bb0 = tid/100, i0 = tid - bb0*100;
  int it1 = tid + 512;
  int bb1 = it1/100, i1 = it1 - bb1*100;
  bool v1ok = (it1 < 800);

  const bool isN = (w >= 5);
  for (int s=0;s<Kc;s++){
    float xp0 = 0.f, xp1 = 0.f;
    if (s < Kc-1){
      xp0 = ws[OFF_WX + (size_t)(b0+bb0)*KWc + (s+1)*Wc + i0];
      if (v1ok) xp1 = ws[OFF_WX + (size_t)(b0+bb1)*KWc + (s+1)*Wc + i1];
    }
    lds_barrier();   // h+x staging ready
    const u16* bBase = bF + (size_t)n16*40 + (size_t)quad*8;
    short8 bx[4];
    #pragma unroll
    for (int c=0;c<4;c++) bx[c] = *(const short8*)(bBase + (size_t)(5+c)*640);
    short8 bh[5];
    #pragma unroll
    for (int c=0;c<5;c++) bh[c] = *(const short8*)(bBase + (size_t)c*640);
    // ---- phase A: wih . x ----
    floatx4 acc[4] = {{0.f,0.f,0.f,0.f},{0.f,0.f,0.f,0.f},{0.f,0.f,0.f,0.f},{0.f,0.f,0.f,0.f}};
    #pragma unroll
    for (int ca=0;ca<4;ca++){
      #pragma unroll
      for (int ti=0;ti<4;ti++)
        acc[ti] = __builtin_amdgcn_mfma_f32_16x16x32_bf16(wihA[ti][ca], bx[ca], acc[ti], 0,0,0);
    }
    if (isN){
      if (n16 < 8){
        #pragma unroll
        for (int ti=0;ti<4;ti++){
          int tile = w*4 + ti;
          if (tile < 30){
            int srb = (tile - 20)*16 + quad*4;
            float* gq = g_np + srb*10 + n16;
            #pragma unroll
            for (int r=0;r<4;r++) gq[r*10] = acc[ti][r];
          }
        }
      }
      #pragma unroll
      for (int ti=0;ti<4;ti++) acc[ti] = (floatx4){0.f,0.f,0.f,0.f};
    }
    // ---- phase B: whh . h, 5 packed chunks ----
    #pragma unroll
    for (int c=0;c<5;c++){
      #pragma unroll
      for (int ti=0;ti<4;ti++)
        acc[ti] = __builtin_amdgcn_mfma_f32_16x16x32_bf16(whhA[ti][c], bh[c], acc[ti], 0,0,0);
    }
    #pragma unroll
    for (int ti=0;ti<4;ti++){
      #pragma unroll
      for (int r=0;r<4;r++) acc[ti][r] += __shfl_xor(acc[ti][r], 8);
    }
    if (n16 < 8){
      #pragma unroll
      for (int ti=0;ti<4;ti++){
        int tile = w*4 + ti;
        if (tile < 30){
          int sec = tile/10;
          int srb = (tile - sec*10)*16 + quad*4;
          if (sec < 2){
            float* gp = g_rz + (sec*160 + srb)*10 + n16;
            #pragma unroll
            for (int r=0;r<4;r++) gp[r*10] = acc[ti][r];
          } else {
            float* gh = g_nh + srb*10 + n16;
            #pragma unroll
            for (int r=0;r<4;r++) gh[r*10] = acc[ti][r];
          }
        }
      }
    }
    lds_barrier();   // gates ready; bF MFMA reads done
    #pragma unroll
    for (int q=0;q<3;q++){
      int task = tid + q*512;
      if (task < 1200){
        int t = task >> 3, bb = task & 7;
        float a_r = g_rz[t*10+bb] + brz_r[q];
        float a_z = g_rz[(160+t)*10+bb] + brz_z[q];
        float r  = 1.f/(1.f+__expf(-a_r));
        float zz = 1.f/(1.f+__expf(-a_z));
        float nx = (g_np[t*10+bb] + bnp_[q]) + r*(g_nh[t*10+bb] + bnh_[q]);
        nx = fminf(fmaxf(nx,-15.f),15.f);
        float e2 = __expf(2.f*nx);
        float n = (e2-1.f)/(e2+1.f);
        float h = (1.f-zz)*n + zz*hst[q];
        hst[q] = h;
        u16 hi = f2us(h); float hif = us2f(hi); u16 lo = f2us(h - hif);
        bF[(t>>5)*640 + bb*40 + (t&31)] = hi;
        bF[(t>>5)*640 + (bb+8)*40 + (t&31)] = lo;
      }
    }
    if (s < Kc-1){
      bF[(5+(i0>>5))*640 + bb0*40 + (i0&31)] = f2us(xp0);
      if (v1ok) bF[(5+(i1>>5))*640 + bb1*40 + (i1&31)] = f2us(xp1);
    }
  }
  #pragma unroll
  for (int q=0;q<3;q++){
    int task = tid + q*512;
    if (task < 1200){
      int t = task >> 3, bb = task & 7;
      out[((size_t)(b0+bb)*Kc + kk)*Hc + t] = hst[q];
    }
  }
}

extern "C" void kernel_launch(void* const* d_in, const int* in_sizes, int n_in,
                              void* d_out, int out_size, void* d_ws, size_t ws_size,
                              hipStream_t stream){
  const float* x        = (const float*)d_in[0];
  const float* y        = (const float*)d_in[1];
  const float* z_noise  = (const float*)d_in[2];
  const float* lin_w    = (const float*)d_in[3];
  const float* lin_b    = (const float*)d_in[4];
  const float* a        = (const float*)d_in[5];
  const float* bias     = (const float*)d_in[6];
  const float* gl_wih   = (const float*)d_in[7];
  const float* gl_whh   = (const float*)d_in[8];
  const float* gl_bih   = (const float*)d_in[9];
  const float* gl_bhh   = (const float*)d_in[10];
  const float* mu_w     = (const float*)d_in[11];
  const float* mu_b     = (const float*)d_in[12];
  const float* std_w    = (const float*)d_in[13];
  const float* std_b    = (const float*)d_in[14];
  const float* net_wih  = (const float*)d_in[15];
  const float* net_whh  = (const float*)d_in[16];
  const float* net_bih  = (const float*)d_in[17];
  const float* net_bhh  = (const float*)d_in[18];
  float* ws = (float*)d_ws;
  float* out = (float*)d_out;

  wx_kernel<<<(Bc*KWc+255)/256, 256, 0, stream>>>(x, lin_w, lin_b, ws);
  attn_kernel<<<Bc*Kc, 256, 0, stream>>>(y, a, bias, ws);
  glproj_kernel<<<(Kc*Bc*H3c+255)/256, 256, 0, stream>>>(gl_wih, gl_bih, ws);
  glgru4_kernel<<<Bc, 512, 0, stream>>>(gl_whh, gl_bhh, ws);
  z_kernel<<<(Bc*Hc+255)/256, 256, 0, stream>>>(z_noise, mu_w, mu_b, std_w, std_b, ws);
  causes3_kernel<<<Kc*4, 512, 0, stream>>>(net_wih, net_whh, net_bih, net_bhh, ws, out);
}

// Round 13
// 449.186 us; speedup vs baseline: 1.2350x; 1.0770x over previous
//
#include <hip/hip_runtime.h>

#define Bc 32
#define Kc 64
#define Wc 100
#define Hc 150
#define H3c 450
#define KWc 6400
#define ALPHAc 0.2f
#define THRESc 0.0002f

typedef unsigned int u32;
typedef unsigned short u16;
typedef __attribute__((ext_vector_type(8))) short short8;   // 8 bf16
typedef __attribute__((ext_vector_type(4))) float floatx4;  // 4 f32 acc

// ---- ws layout (float offsets), 4.55 MB ----
#define OFF_WX      0u          // 204800  Wx (B,K,W) fp32
#define OFF_CS      204800u     // 2048    causesum (B,K)
#define OFF_GX      206848u     // 921600  gl proj (s,b,g)
#define OFF_HT      1128448u    // 4800    h_t (B,H)
#define OFF_Z       1133248u    // 4800    z (B,H)

__device__ __forceinline__ float us2f(u16 u){ u32 x=((u32)u)<<16; return __uint_as_float(x); }
__device__ __forceinline__ u16 f2us(float f){
  u32 x = __float_as_uint(f);
  u32 r = (x + 0x7fffu + ((x>>16)&1u)) >> 16;   // RNE bf16
  return (u16)r;
}

// LDS-only barrier: skips the vmcnt(0) drain __syncthreads would emit; global
// loads issued before it stay in flight (consumed via register deps).
__device__ __forceinline__ void lds_barrier(){
  __builtin_amdgcn_sched_barrier(0);
  asm volatile("s_waitcnt lgkmcnt(0)" ::: "memory");
  __builtin_amdgcn_s_barrier();
  __builtin_amdgcn_sched_barrier(0);
}

// ---------- Wx = x @ lin_w.T + lin_b ----------
__global__ void wx_kernel(const float* __restrict__ x, const float* __restrict__ lin_w,
                          const float* __restrict__ lin_b, float* __restrict__ ws){
  int o = blockIdx.x*256 + threadIdx.x;
  if (o >= Bc*KWc) return;
  int i = o % Wc;
  int bk = o / Wc;
  const float4* xr = (const float4*)(x + bk*Wc);
  const float4* wr = (const float4*)(lin_w + i*Wc);
  float acc = lin_b[i];
  #pragma unroll
  for (int j=0;j<25;j++){
    float4 xv = xr[j], wv = wr[j];
    acc += xv.x*wv.x + xv.y*wv.y + xv.z*wv.z + xv.w*wv.w;
  }
  ws[OFF_WX + o] = acc;
}

// ---------- attention softmax + thresholded sum (float4, __expf, log-threshold) ----------
__global__ void attn_kernel(const float* __restrict__ y, const float* __restrict__ a,
                            const float* __restrict__ bias, float* __restrict__ ws){
  __shared__ __align__(16) float e_l[KWc];
  __shared__ float red[4];
  int row = blockIdx.x;          // b*64 + k
  int b = row >> 6, k = row & 63;
  int tid = threadIdx.x;
  float a0 = a[0], a1 = a[1];
  float yv = y[row];
  const float4* v4  = (const float4*)(ws + OFF_WX + (size_t)b*KWc);
  const float4* br4 = (const float4*)(bias + (size_t)k*KWc);
  float4* e4 = (float4*)e_l;
  float ay = a0*yv;
  float m = -3.4e38f;
  for (int j=tid; j<KWc/4; j+=256){
    float4 vv = v4[j], bb = br4[j];
    float4 e;
    e.x = ay + a1*vv.x + bb.x; e.x = (e.x>=0.f)?e.x:ALPHAc*e.x;
    e.y = ay + a1*vv.y + bb.y; e.y = (e.y>=0.f)?e.y:ALPHAc*e.y;
    e.z = ay + a1*vv.z + bb.z; e.z = (e.z>=0.f)?e.z:ALPHAc*e.z;
    e.w = ay + a1*vv.w + bb.w; e.w = (e.w>=0.f)?e.w:ALPHAc*e.w;
    e4[j] = e;
    m = fmaxf(m, fmaxf(fmaxf(e.x,e.y), fmaxf(e.z,e.w)));
  }
  for (int o=32;o;o>>=1) m = fmaxf(m, __shfl_down(m, o));
  if ((tid&63)==0) red[tid>>6] = m;
  __syncthreads();
  m = fmaxf(fmaxf(red[0],red[1]), fmaxf(red[2],red[3]));
  __syncthreads();
  float ssum = 0.f;
  for (int j=tid; j<KWc/4; j+=256){
    float4 e = e4[j];
    ssum += __expf(e.x-m) + __expf(e.y-m) + __expf(e.z-m) + __expf(e.w-m);
  }
  for (int o=32;o;o>>=1) ssum += __shfl_down(ssum, o);
  if ((tid&63)==0) red[tid>>6] = ssum;
  __syncthreads();
  float s = red[0]+red[1]+red[2]+red[3];
  float thr = m + logf(THRESc * s);
  float cs = 0.f;
  for (int j=tid; j<KWc/4; j+=256){
    float4 e = e4[j];
    float4 vv = v4[j];
    if (e.x >= thr) cs += vv.x;
    if (e.y >= thr) cs += vv.y;
    if (e.z >= thr) cs += vv.z;
    if (e.w >= thr) cs += vv.w;
  }
  for (int o=32;o;o>>=1) cs += __shfl_down(cs, o);
  if ((tid&63)==0) red[tid>>6] = cs;
  __syncthreads();
  if (tid==0) ws[OFF_CS + row] = red[0]+red[1]+red[2]+red[3];
}

// ---------- gl input projection ----------
__global__ void glproj_kernel(const float* __restrict__ gl_wih, const float* __restrict__ gl_bih,
                              float* __restrict__ ws){
  int o = blockIdx.x*256 + threadIdx.x;
  if (o >= Kc*Bc*H3c) return;
  int g = o % H3c;
  int t = o / H3c;               // s*32 + b
  int b = t & 31, s = t >> 5;
  float cs = ws[OFF_CS + b*Kc + s];
  const float4* xr = (const float4*)(ws + OFF_WX + b*KWc + s*Wc);
  const float4* wr = (const float4*)(gl_wih + g*Wc);
  float acc = gl_bih[g];
  #pragma unroll
  for (int j=0;j<25;j++){
    float4 wv = wr[j], xv = xr[j];
    acc += (xv.x+cs)*wv.x + (xv.y+cs)*wv.y + (xv.z+cs)*wv.z + (xv.w+cs)*wv.w;
  }
  ws[OFF_GX + o] = acc;
}

// ---------- gl recurrent GRU v15: f32 reg weights, 2 threads/row, 1024 thr, z fused ----------
// v14's bf16 unpack cost ~2.5 inst/MAC at 2 waves/SIMD. Now: thread (half,row) owns
// 76 f32 weights (no unpack, ~1 inst/MAC), 16 waves (4/SIMD) hide chain+barrier
// latency, halves write partial dots, 150 finishers do gates. Epilogue computes
// z = mu + exp(0.5*lv)*noise in-block (h already in LDS) -> z_kernel launch removed.
__global__ void __launch_bounds__(1024,1) glgru4_kernel(
    const float* __restrict__ gl_whh, const float* __restrict__ gl_bhh,
    const float* __restrict__ z_noise, const float* __restrict__ mu_w,
    const float* __restrict__ mu_b, const float* __restrict__ std_w,
    const float* __restrict__ std_b, float* __restrict__ ws){
  __shared__ __align__(16) float hbuf[2][152];    // f32 h, rows 150/151 stay 0
  __shared__ __align__(16) float dotb[2][3][152]; // [half][gate][t]
  int b = blockIdx.x;            // one batch per block
  int tid = threadIdx.x;
  bool dotter = (tid < 900);
  int half = (tid >= 450) ? 1 : 0;
  int row  = dotter ? (tid - half*450) : 0;   // 0..449 = g*150+t
  int g = row/150, t = row - g*150;

  // prologue: this thread's half-row of gl_whh in f32 regs (76 = 19 float4 spans;
  // half1 covers k 76..151 with wreg[74..75]=0 matching hbuf's zero rows 150/151)
  float wreg[76];
  if (dotter){
    const float* wr = gl_whh + (size_t)row*Hc + half*76;
    #pragma unroll
    for (int i=0;i<37;i++){                      // 74 elems via 8B loads (row base is 8B-aligned)
      float2 v = *(const float2*)(wr + 2*i);
      wreg[2*i] = v.x; wreg[2*i+1] = v.y;
    }
    if (!half){ float2 v = *(const float2*)(wr + 74); wreg[74]=v.x; wreg[75]=v.y; }
    else      { wreg[74]=0.f; wreg[75]=0.f; }    // k=150,151 -> zero
  }
  if (tid < 152){ hbuf[0][tid] = 0.f; hbuf[1][tid] = 0.f; }

  float bh_r=0.f, bh_z=0.f, bh_n=0.f, hreg=0.f;
  if (tid < Hc){
    bh_r = gl_bhh[tid]; bh_z = gl_bhh[Hc+tid]; bh_n = gl_bhh[2*Hc+tid];
  }
  __syncthreads();

  for (int s=0;s<Kc;s++){
    int rb = s & 1;
    // finisher gx loads: issued first, in flight across the dot phase + barrier
    float gxr=0.f, gxz=0.f, gxn=0.f;
    if (tid < Hc){
      const float* gp = ws + OFF_GX + (size_t)(s*Bc + b)*H3c;
      gxr = gp[tid]; gxz = gp[Hc+tid]; gxn = gp[2*Hc+tid];
    }
    if (dotter){
      const float* hb = &hbuf[rb][half*76];      // 16B-aligned (76*4=304)
      float a0=0.f,a1=0.f,a2=0.f,a3=0.f;
      #pragma unroll
      for (int i=0;i<19;i++){
        float4 h4 = *(const float4*)(hb + 4*i);  // LDS broadcast
        a0 += wreg[4*i]  *h4.x;
        a1 += wreg[4*i+1]*h4.y;
        a2 += wreg[4*i+2]*h4.z;
        a3 += wreg[4*i+3]*h4.w;
      }
      dotb[half][g][t] = (a0+a1)+(a2+a3);
    }
    lds_barrier();   // dots ready
    if (tid < Hc){
      float dr = dotb[0][0][tid] + dotb[1][0][tid];
      float dz = dotb[0][1][tid] + dotb[1][1][tid];
      float dn = dotb[0][2][tid] + dotb[1][2][tid];
      float a_r = gxr + dr + bh_r;
      float a_z = gxz + dz + bh_z;
      float rr = 1.f/(1.f+__expf(-a_r));
      float zz = 1.f/(1.f+__expf(-a_z));
      float nx = gxn + rr*(dn + bh_n);
      nx = fminf(fmaxf(nx,-15.f),15.f);
      float e2 = __expf(2.f*nx);
      float n = (e2-1.f)/(e2+1.f);
      float h = (1.f-zz)*n + zz*hreg;
      hreg = h;
      hbuf[rb^1][tid] = h;
    }
    lds_barrier();   // h ready; dotb consumed (WAR safe)
  }
  // final h is in hbuf[0] (s=63: rb=1, wrote hbuf[0]); also write HT (cheap, debug aid)
  if (tid < Hc) ws[OFF_HT + (size_t)b*Hc + tid] = hreg;

  // ---- fused z = mu + exp(0.5*log_var)*noise ----
  if (tid < 300){
    int which = tid/150, tt = tid - which*150;
    const float* wrow = (which ? std_w : mu_w) + (size_t)tt*Hc;
    float acc = which ? std_b[tt] : mu_b[tt];
    const float* hb = hbuf[0];
    #pragma unroll
    for (int i=0;i<75;i++){
      float2 wv = *(const float2*)(wrow + 2*i);
      float2 hv = *(const float2*)(hb + 2*i);
      acc += wv.x*hv.x + wv.y*hv.y;
    }
    dotb[0][which][tt] = acc;    // reuse dotb: [0][0]=mu, [0][1]=log_var
  }
  lds_barrier();
  if (tid < Hc){
    float mu = dotb[0][0][tid], lv = dotb[0][1][tid];
    float sg = expf(0.5f*lv);
    ws[OFF_Z + (size_t)b*Hc + tid] = mu + sg*z_noise[(size_t)b*Hc + tid];
  }
}

// ---------- causes v13 (kept): round-7 skeleton + hi/lo packed B-cols ----------
__global__ void __launch_bounds__(512,1) causes3_kernel(
    const float* __restrict__ net_wih, const float* __restrict__ net_whh,
    const float* __restrict__ net_bih, const float* __restrict__ net_bhh,
    const float* __restrict__ ws, float* __restrict__ out){
  __shared__ __align__(16) u16 bF[9*16*40];    // h: 5 chunks packed; x: 4 chunks
  __shared__ float g_rz[320*10];
  __shared__ float g_nh[160*10];
  __shared__ float g_np[160*10];
  int kk = blockIdx.x & 63, bg = blockIdx.x >> 6, b0 = bg*8;
  int tid = threadIdx.x;
  int w = tid >> 6, lane = tid & 63, quad = lane >> 4, n16 = lane & 15;
  const float* whhk = net_whh + (size_t)kk*H3c*Hc;
  const float* wihk = net_wih + (size_t)kk*H3c*Wc;
  const float* bihk = net_bih + kk*H3c;
  const float* bhhk = net_bhh + kk*H3c;

  short8 whhA[4][5], wihA[4][4];
  #pragma unroll
  for (int ti=0; ti<4; ti++){
    int tile = w*4 + ti;
    int sec = tile/10;
    int sr = (tile - sec*10)*16 + n16;
    bool rowok = (tile < 30) && (sr < Hc);
    int grow = (sec<3 ? sec : 2)*Hc + sr;
    #pragma unroll
    for (int c=0;c<5;c++){
      union { short8 v; u16 u[8]; } t8;
      #pragma unroll
      for (int j=0;j<8;j++){
        int k = c*32 + quad*8 + j;
        float v = (rowok && k < Hc) ? whhk[(size_t)grow*Hc + k] : 0.f;
        t8.u[j] = f2us(v);
      }
      whhA[ti][c] = t8.v;
    }
    #pragma unroll
    for (int c=0;c<4;c++){
      union { short8 v; u16 u[8]; } t8;
      #pragma unroll
      for (int j=0;j<8;j++){
        int k = c*32 + quad*8 + j;
        float v = (rowok && k < Wc) ? wihk[(size_t)grow*Wc + k] : 0.f;
        t8.u[j] = f2us(v);
      }
      wihA[ti][c] = t8.v;
    }
  }

  for (int i=tid; i<9*16*40/2; i+=512) ((u32*)bF)[i] = 0u;

  float hst[3] = {0.f,0.f,0.f};
  float brz_r[3], brz_z[3], bnh_[3], bnp_[3];
  #pragma unroll
  for (int q=0;q<3;q++){
    int task = tid + q*512;
    if (task < 1200){
      int t = task >> 3, bb = task & 7;
      float h = ws[OFF_Z + (b0+bb)*Hc + t];
      hst[q] = h;
      brz_r[q] = bhhk[t]      + bihk[t];
      brz_z[q] = bhhk[Hc+t]   + bihk[Hc+t];
      bnh_[q]  = bhhk[2*Hc+t];
      bnp_[q]  = bihk[2*Hc+t];
      u16 hi = f2us(h); float hif = us2f(hi); u16 lo = f2us(h - hif);
      bF[(t>>5)*640 + bb*40 + (t&31)] = hi;
      bF[(t>>5)*640 + (bb+8)*40 + (t&31)] = lo;
    }
  }
  for (int it=tid; it<800; it+=512){
    int bb = it/100, i = it - bb*100;
    float xv = ws[OFF_WX + (b0+bb)*KWc + i];
    bF[(5+(i>>5))*640 + bb*40 + (i&31)] = f2us(xv);
  }

  int bb0 = tid/100, i0 = tid - bb0*100;
  int it1 = tid + 512;
  int bb1 = it1/100, i1 = it1 - bb1*100;
  bool v1ok = (it1 < 800);

  const bool isN = (w >= 5);
  for (int s=0;s<Kc;s++){
    float xp0 = 0.f, xp1 = 0.f;
    if (s < Kc-1){
      xp0 = ws[OFF_WX + (size_t)(b0+bb0)*KWc + (s+1)*Wc + i0];
      if (v1ok) xp1 = ws[OFF_WX + (size_t)(b0+bb1)*KWc + (s+1)*Wc + i1];
    }
    lds_barrier();   // h+x staging ready
    const u16* bBase = bF + (size_t)n16*40 + (size_t)quad*8;
    short8 bx[4];
    #pragma unroll
    for (int c=0;c<4;c++) bx[c] = *(const short8*)(bBase + (size_t)(5+c)*640);
    short8 bh[5];
    #pragma unroll
    for (int c=0;c<5;c++) bh[c] = *(const short8*)(bBase + (size_t)c*640);
    // ---- phase A: wih . x ----
    floatx4 acc[4] = {{0.f,0.f,0.f,0.f},{0.f,0.f,0.f,0.f},{0.f,0.f,0.f,0.f},{0.f,0.f,0.f,0.f}};
    #pragma unroll
    for (int ca=0;ca<4;ca++){
      #pragma unroll
      for (int ti=0;ti<4;ti++)
        acc[ti] = __builtin_amdgcn_mfma_f32_16x16x32_bf16(wihA[ti][ca], bx[ca], acc[ti], 0,0,0);
    }
    if (isN){
      if (n16 < 8){
        #pragma unroll
        for (int ti=0;ti<4;ti++){
          int tile = w*4 + ti;
          if (tile < 30){
            int srb = (tile - 20)*16 + quad*4;
            float* gq = g_np + srb*10 + n16;
            #pragma unroll
            for (int r=0;r<4;r++) gq[r*10] = acc[ti][r];
          }
        }
      }
      #pragma unroll
      for (int ti=0;ti<4;ti++) acc[ti] = (floatx4){0.f,0.f,0.f,0.f};
    }
    // ---- phase B: whh . h, 5 packed chunks ----
    #pragma unroll
    for (int c=0;c<5;c++){
      #pragma unroll
      for (int ti=0;ti<4;ti++)
        acc[ti] = __builtin_amdgcn_mfma_f32_16x16x32_bf16(whhA[ti][c], bh[c], acc[ti], 0,0,0);
    }
    #pragma unroll
    for (int ti=0;ti<4;ti++){
      #pragma unroll
      for (int r=0;r<4;r++) acc[ti][r] += __shfl_xor(acc[ti][r], 8);
    }
    if (n16 < 8){
      #pragma unroll
      for (int ti=0;ti<4;ti++){
        int tile = w*4 + ti;
        if (tile < 30){
          int sec = tile/10;
          int srb = (tile - sec*10)*16 + quad*4;
          if (sec < 2){
            float* gp = g_rz + (sec*160 + srb)*10 + n16;
            #pragma unroll
            for (int r=0;r<4;r++) gp[r*10] = acc[ti][r];
          } else {
            float* gh = g_nh + srb*10 + n16;
            #pragma unroll
            for (int r=0;r<4;r++) gh[r*10] = acc[ti][r];
          }
        }
      }
    }
    lds_barrier();   // gates ready; bF MFMA reads done
    #pragma unroll
    for (int q=0;q<3;q++){
      int task = tid + q*512;
      if (task < 1200){
        int t = task >> 3, bb = task & 7;
        float a_r = g_rz[t*10+bb] + brz_r[q];
        float a_z = g_rz[(160+t)*10+bb] + brz_z[q];
        float r  = 1.f/(1.f+__expf(-a_r));
        float zz = 1.f/(1.f+__expf(-a_z));
        float nx = (g_np[t*10+bb] + bnp_[q]) + r*(g_nh[t*10+bb] + bnh_[q]);
        nx = fminf(fmaxf(nx,-15.f),15.f);
        float e2 = __expf(2.f*nx);
        float n = (e2-1.f)/(e2+1.f);
        float h = (1.f-zz)*n + zz*hst[q];
        hst[q] = h;
        u16 hi = f2us(h); float hif = us2f(hi); u16 lo = f2us(h - hif);
        bF[(t>>5)*640 + bb*40 + (t&31)] = hi;
        bF[(t>>5)*640 + (bb+8)*40 + (t&31)] = lo;
      }
    }
    if (s < Kc-1){
      bF[(5+(i0>>5))*640 + bb0*40 + (i0&31)] = f2us(xp0);
      if (v1ok) bF[(5+(i1>>5))*640 + bb1*40 + (i1&31)] = f2us(xp1);
    }
  }
  #pragma unroll
  for (int q=0;q<3;q++){
    int task = tid + q*512;
    if (task < 1200){
      int t = task >> 3, bb = task & 7;
      out[((size_t)(b0+bb)*Kc + kk)*Hc + t] = hst[q];
    }
  }
}

extern "C" void kernel_launch(void* const* d_in, const int* in_sizes, int n_in,
                              void* d_out, int out_size, void* d_ws, size_t ws_size,
                              hipStream_t stream){
  const float* x        = (const float*)d_in[0];
  const float* y        = (const float*)d_in[1];
  const float* z_noise  = (const float*)d_in[2];
  const float* lin_w    = (const float*)d_in[3];
  const float* lin_b    = (const float*)d_in[4];
  const float* a        = (const float*)d_in[5];
  const float* bias     = (const float*)d_in[6];
  const float* gl_wih   = (const float*)d_in[7];
  const float* gl_whh   = (const float*)d_in[8];
  const float* gl_bih   = (const float*)d_in[9];
  const float* gl_bhh   = (const float*)d_in[10];
  const float* mu_w     = (const float*)d_in[11];
  const float* mu_b     = (const float*)d_in[12];
  const float* std_w    = (const float*)d_in[13];
  const float* std_b    = (const float*)d_in[14];
  const float* net_wih  = (const float*)d_in[15];
  const float* net_whh  = (const float*)d_in[16];
  const float* net_bih  = (const float*)d_in[17];
  const float* net_bhh  = (const float*)d_in[18];
  float* ws = (float*)d_ws;
  float* out = (float*)d_out;

  wx_kernel<<<(Bc*KWc+255)/256, 256, 0, stream>>>(x, lin_w, lin_b, ws);
  attn_kernel<<<Bc*Kc, 256, 0, stream>>>(y, a, bias, ws);
  glproj_kernel<<<(Kc*Bc*H3c+255)/256, 256, 0, stream>>>(gl_wih, gl_bih, ws);
  glgru4_kernel<<<Bc, 1024, 0, stream>>>(gl_whh, gl_bhh, z_noise, mu_w, mu_b, std_w, std_b, ws);
  causes3_kernel<<<Kc*4, 512, 0, stream>>>(net_wih, net_whh, net_bih, net_bhh, ws, out);
}

// Round 15
// 438.034 us; speedup vs baseline: 1.2665x; 1.0255x over previous
//
#include <hip/hip_runtime.h>

#define Bc 32
#define Kc 64
#define Wc 100
#define Hc 150
#define H3c 450
#define KWc 6400
#define ALPHAc 0.2f
#define THRESc 0.0002f

typedef unsigned int u32;
typedef unsigned short u16;
typedef __attribute__((ext_vector_type(8))) short short8;   // 8 bf16
typedef __attribute__((ext_vector_type(4))) float floatx4;  // 4 f32 acc

// ---- ws layout (float offsets), 4.55 MB ----
#define OFF_WX      0u          // 204800  Wx (B,K,W) fp32
#define OFF_CS      204800u     // 2048    causesum (B,K)
#define OFF_GX      206848u     // 921600  gl proj (s,b,g)
#define OFF_HT      1128448u    // 4800    h_t (B,H)
#define OFF_Z       1133248u    // 4800    z (B,H)

__device__ __forceinline__ float us2f(u16 u){ u32 x=((u32)u)<<16; return __uint_as_float(x); }
__device__ __forceinline__ u16 f2us(float f){
  u32 x = __float_as_uint(f);
  u32 r = (x + 0x7fffu + ((x>>16)&1u)) >> 16;   // RNE bf16
  return (u16)r;
}

// LDS-only barrier: skips the vmcnt(0) drain __syncthreads would emit; global
// loads issued before it stay in flight (consumed via register deps).
__device__ __forceinline__ void lds_barrier(){
  __builtin_amdgcn_sched_barrier(0);
  asm volatile("s_waitcnt lgkmcnt(0)" ::: "memory");
  __builtin_amdgcn_s_barrier();
  __builtin_amdgcn_sched_barrier(0);
}

// ---------- Wx = x @ lin_w.T + lin_b ----------
__global__ void wx_kernel(const float* __restrict__ x, const float* __restrict__ lin_w,
                          const float* __restrict__ lin_b, float* __restrict__ ws){
  int o = blockIdx.x*256 + threadIdx.x;
  if (o >= Bc*KWc) return;
  int i = o % Wc;
  int bk = o / Wc;
  const float4* xr = (const float4*)(x + bk*Wc);
  const float4* wr = (const float4*)(lin_w + i*Wc);
  float acc = lin_b[i];
  #pragma unroll
  for (int j=0;j<25;j++){
    float4 xv = xr[j], wv = wr[j];
    acc += xv.x*wv.x + xv.y*wv.y + xv.z*wv.z + xv.w*wv.w;
  }
  ws[OFF_WX + o] = acc;
}

// ---------- attention softmax + thresholded sum (float4, __expf, log-threshold) ----------
__global__ void attn_kernel(const float* __restrict__ y, const float* __restrict__ a,
                            const float* __restrict__ bias, float* __restrict__ ws){
  __shared__ __align__(16) float e_l[KWc];
  __shared__ float red[4];
  int row = blockIdx.x;          // b*64 + k
  int b = row >> 6, k = row & 63;
  int tid = threadIdx.x;
  float a0 = a[0], a1 = a[1];
  float yv = y[row];
  const float4* v4  = (const float4*)(ws + OFF_WX + (size_t)b*KWc);
  const float4* br4 = (const float4*)(bias + (size_t)k*KWc);
  float4* e4 = (float4*)e_l;
  float ay = a0*yv;
  float m = -3.4e38f;
  for (int j=tid; j<KWc/4; j+=256){
    float4 vv = v4[j], bb = br4[j];
    float4 e;
    e.x = ay + a1*vv.x + bb.x; e.x = (e.x>=0.f)?e.x:ALPHAc*e.x;
    e.y = ay + a1*vv.y + bb.y; e.y = (e.y>=0.f)?e.y:ALPHAc*e.y;
    e.z = ay + a1*vv.z + bb.z; e.z = (e.z>=0.f)?e.z:ALPHAc*e.z;
    e.w = ay + a1*vv.w + bb.w; e.w = (e.w>=0.f)?e.w:ALPHAc*e.w;
    e4[j] = e;
    m = fmaxf(m, fmaxf(fmaxf(e.x,e.y), fmaxf(e.z,e.w)));
  }
  for (int o=32;o;o>>=1) m = fmaxf(m, __shfl_down(m, o));
  if ((tid&63)==0) red[tid>>6] = m;
  __syncthreads();
  m = fmaxf(fmaxf(red[0],red[1]), fmaxf(red[2],red[3]));
  __syncthreads();
  float ssum = 0.f;
  for (int j=tid; j<KWc/4; j+=256){
    float4 e = e4[j];
    ssum += __expf(e.x-m) + __expf(e.y-m) + __expf(e.z-m) + __expf(e.w-m);
  }
  for (int o=32;o;o>>=1) ssum += __shfl_down(ssum, o);
  if ((tid&63)==0) red[tid>>6] = ssum;
  __syncthreads();
  float s = red[0]+red[1]+red[2]+red[3];
  float thr = m + logf(THRESc * s);
  float cs = 0.f;
  for (int j=tid; j<KWc/4; j+=256){
    float4 e = e4[j];
    float4 vv = v4[j];
    if (e.x >= thr) cs += vv.x;
    if (e.y >= thr) cs += vv.y;
    if (e.z >= thr) cs += vv.z;
    if (e.w >= thr) cs += vv.w;
  }
  for (int o=32;o;o>>=1) cs += __shfl_down(cs, o);
  if ((tid&63)==0) red[tid>>6] = cs;
  __syncthreads();
  if (tid==0) ws[OFF_CS + row] = red[0]+red[1]+red[2]+red[3];
}

// ---------- gl input projection ----------
__global__ void glproj_kernel(const float* __restrict__ gl_wih, const float* __restrict__ gl_bih,
                              float* __restrict__ ws){
  int o = blockIdx.x*256 + threadIdx.x;
  if (o >= Kc*Bc*H3c) return;
  int g = o % H3c;
  int t = o / H3c;               // s*32 + b
  int b = t & 31, s = t >> 5;
  float cs = ws[OFF_CS + b*Kc + s];
  const float4* xr = (const float4*)(ws + OFF_WX + b*KWc + s*Wc);
  const float4* wr = (const float4*)(gl_wih + g*Wc);
  float acc = gl_bih[g];
  #pragma unroll
  for (int j=0;j<25;j++){
    float4 wv = wr[j], xv = xr[j];
    acc += (xv.x+cs)*wv.x + (xv.y+cs)*wv.y + (xv.z+cs)*wv.z + (xv.w+cs)*wv.w;
  }
  ws[OFF_GX + o] = acc;
}

// ---------- gl recurrent GRU v15: f32 reg weights, 2 threads/row, 1024 thr, z fused ----------
__global__ void __launch_bounds__(1024,1) glgru4_kernel(
    const float* __restrict__ gl_whh, const float* __restrict__ gl_bhh,
    const float* __restrict__ z_noise, const float* __restrict__ mu_w,
    const float* __restrict__ mu_b, const float* __restrict__ std_w,
    const float* __restrict__ std_b, float* __restrict__ ws){
  __shared__ __align__(16) float hbuf[2][152];    // f32 h, rows 150/151 stay 0
  __shared__ __align__(16) float dotb[2][3][152]; // [half][gate][t]
  int b = blockIdx.x;            // one batch per block
  int tid = threadIdx.x;
  bool dotter = (tid < 900);
  int half = (tid >= 450) ? 1 : 0;
  int row  = dotter ? (tid - half*450) : 0;   // 0..449 = g*150+t
  int g = row/150, t = row - g*150;

  float wreg[76];
  if (dotter){
    const float* wr = gl_whh + (size_t)row*Hc + half*76;
    #pragma unroll
    for (int i=0;i<37;i++){
      float2 v = *(const float2*)(wr + 2*i);
      wreg[2*i] = v.x; wreg[2*i+1] = v.y;
    }
    if (!half){ float2 v = *(const float2*)(wr + 74); wreg[74]=v.x; wreg[75]=v.y; }
    else      { wreg[74]=0.f; wreg[75]=0.f; }
  }
  if (tid < 152){ hbuf[0][tid] = 0.f; hbuf[1][tid] = 0.f; }

  float bh_r=0.f, bh_z=0.f, bh_n=0.f, hreg=0.f;
  if (tid < Hc){
    bh_r = gl_bhh[tid]; bh_z = gl_bhh[Hc+tid]; bh_n = gl_bhh[2*Hc+tid];
  }
  __syncthreads();

  for (int s=0;s<Kc;s++){
    int rb = s & 1;
    float gxr=0.f, gxz=0.f, gxn=0.f;
    if (tid < Hc){
      const float* gp = ws + OFF_GX + (size_t)(s*Bc + b)*H3c;
      gxr = gp[tid]; gxz = gp[Hc+tid]; gxn = gp[2*Hc+tid];
    }
    if (dotter){
      const float* hb = &hbuf[rb][half*76];
      float a0=0.f,a1=0.f,a2=0.f,a3=0.f;
      #pragma unroll
      for (int i=0;i<19;i++){
        float4 h4 = *(const float4*)(hb + 4*i);
        a0 += wreg[4*i]  *h4.x;
        a1 += wreg[4*i+1]*h4.y;
        a2 += wreg[4*i+2]*h4.z;
        a3 += wreg[4*i+3]*h4.w;
      }
      dotb[half][g][t] = (a0+a1)+(a2+a3);
    }
    lds_barrier();   // dots ready
    if (tid < Hc){
      float dr = dotb[0][0][tid] + dotb[1][0][tid];
      float dz = dotb[0][1][tid] + dotb[1][1][tid];
      float dn = dotb[0][2][tid] + dotb[1][2][tid];
      float a_r = gxr + dr + bh_r;
      float a_z = gxz + dz + bh_z;
      float rr = 1.f/(1.f+__expf(-a_r));
      float zz = 1.f/(1.f+__expf(-a_z));
      float nx = gxn + rr*(dn + bh_n);
      nx = fminf(fmaxf(nx,-15.f),15.f);
      float e2 = __expf(2.f*nx);
      float n = (e2-1.f)/(e2+1.f);
      float h = (1.f-zz)*n + zz*hreg;
      hreg = h;
      hbuf[rb^1][tid] = h;
    }
    lds_barrier();   // h ready; dotb consumed (WAR safe)
  }
  if (tid < Hc) ws[OFF_HT + (size_t)b*Hc + tid] = hreg;

  // ---- fused z = mu + exp(0.5*log_var)*noise ----
  if (tid < 300){
    int which = tid/150, tt = tid - which*150;
    const float* wrow = (which ? std_w : mu_w) + (size_t)tt*Hc;
    float acc = which ? std_b[tt] : mu_b[tt];
    const float* hb = hbuf[0];
    #pragma unroll
    for (int i=0;i<75;i++){
      float2 wv = *(const float2*)(wrow + 2*i);
      float2 hv = *(const float2*)(hb + 2*i);
      acc += wv.x*hv.x + wv.y*hv.y;
    }
    dotb[0][which][tt] = acc;
  }
  lds_barrier();
  if (tid < Hc){
    float mu = dotb[0][0][tid], lv = dotb[0][1][tid];
    float sg = expf(0.5f*lv);
    ws[OFF_Z + (size_t)b*Hc + tid] = mu + sg*z_noise[(size_t)b*Hc + tid];
  }
}

// ---------- causes v14: v13 + vectorized weight prologue + dual-dump (no ds_bpermute) ----------
// Prologue: 288 scalar gathers/thread -> 80 float2 (whh, rows 8B-aligned) + 32 float4
// (wih, rows 16B-aligned, k-bases mult of 4). Merge: shfl_xor(8) was 16 ds_bpermute+add
// per thread/step; now all 16 lanes dump partials (hi lanes 0-7, lo lanes 8-15) to
// stride-17 g-arrays and the gate phase adds the pair -- same sum, same order.
__global__ void __launch_bounds__(512,1) causes3_kernel(
    const float* __restrict__ net_wih, const float* __restrict__ net_whh,
    const float* __restrict__ net_bih, const float* __restrict__ net_bhh,
    const float* __restrict__ ws, float* __restrict__ out){
  __shared__ __align__(16) u16 bF[9*16*40];    // h: 5 chunks packed; x: 4 chunks
  __shared__ float g_rz[320*17];               // [row][16 lanes], stride 17
  __shared__ float g_nh[160*17];
  __shared__ float g_np[160*10];
  int kk = blockIdx.x & 63, bg = blockIdx.x >> 6, b0 = bg*8;
  int tid = threadIdx.x;
  int w = tid >> 6, lane = tid & 63, quad = lane >> 4, n16 = lane & 15;
  const float* whhk = net_whh + (size_t)kk*H3c*Hc;
  const float* wihk = net_wih + (size_t)kk*H3c*Wc;
  const float* bihk = net_bih + kk*H3c;
  const float* bhhk = net_bhh + kk*H3c;

  short8 whhA[4][5], wihA[4][4];
  #pragma unroll
  for (int ti=0; ti<4; ti++){
    int tile = w*4 + ti;
    int sec = tile/10;
    int sr = (tile - sec*10)*16 + n16;
    bool rowok = (tile < 30) && (sr < Hc);
    int grow = (sec<3 ? sec : 2)*Hc + sr;
    const float* wr = whhk + (size_t)grow*Hc;     // 600B stride: 8B-aligned
    #pragma unroll
    for (int c=0;c<5;c++){
      union { short8 v; u16 u[8]; } t8;
      #pragma unroll
      for (int j2=0;j2<4;j2++){
        int kk2 = c*32 + quad*8 + j2*2;
        float2 wv = (rowok && (kk2+1) < Hc) ? *(const float2*)(wr + kk2) : make_float2(0.f,0.f);
        t8.u[j2*2]   = f2us(wv.x);
        t8.u[j2*2+1] = f2us(wv.y);
      }
      whhA[ti][c] = t8.v;
    }
    const float* wr2 = wihk + (size_t)grow*Wc;    // 400B stride: 16B-aligned
    #pragma unroll
    for (int c=0;c<4;c++){
      union { short8 v; u16 u[8]; } t8;
      #pragma unroll
      for (int j4=0;j4<2;j4++){
        int kb = c*32 + quad*8 + j4*4;            // mult of 4 -> 16B-aligned; kb<100 => kb<=96 valid span
        float4 wv = (rowok && kb < Wc) ? *(const float4*)(wr2 + kb) : make_float4(0.f,0.f,0.f,0.f);
        t8.u[j4*4]   = f2us(wv.x);
        t8.u[j4*4+1] = f2us(wv.y);
        t8.u[j4*4+2] = f2us(wv.z);
        t8.u[j4*4+3] = f2us(wv.w);
      }
      wihA[ti][c] = t8.v;
    }
  }

  for (int i=tid; i<9*16*40/2; i+=512) ((u32*)bF)[i] = 0u;

  float hst[3] = {0.f,0.f,0.f};
  float brz_r[3], brz_z[3], bnh_[3], bnp_[3];
  #pragma unroll
  for (int q=0;q<3;q++){
    int task = tid + q*512;
    if (task < 1200){
      int t = task >> 3, bb = task & 7;
      float h = ws[OFF_Z + (b0+bb)*Hc + t];
      hst[q] = h;
      brz_r[q] = bhhk[t]      + bihk[t];
      brz_z[q] = bhhk[Hc+t]   + bihk[Hc+t];
      bnh_[q]  = bhhk[2*Hc+t];
      bnp_[q]  = bihk[2*Hc+t];
      u16 hi = f2us(h); float hif = us2f(hi); u16 lo = f2us(h - hif);
      bF[(t>>5)*640 + bb*40 + (t&31)] = hi;
      bF[(t>>5)*640 + (bb+8)*40 + (t&31)] = lo;
    }
  }
  for (int it=tid; it<800; it+=512){
    int bb = it/100, i = it - bb*100;
    float xv = ws[OFF_WX + (b0+bb)*KWc + i];
    bF[(5+(i>>5))*640 + bb*40 + (i&31)] = f2us(xv);
  }

  int bb0 = tid/100, i0 = tid - bb0*100;
  int it1 = tid + 512;
  int bb1 = it1/100, i1 = it1 - bb1*100;
  bool v1ok = (it1 < 800);

  const bool isN = (w >= 5);
  for (int s=0;s<Kc;s++){
    float xp0 = 0.f, xp1 = 0.f;
    if (s < Kc-1){
      xp0 = ws[OFF_WX + (size_t)(b0+bb0)*KWc + (s+1)*Wc + i0];
      if (v1ok) xp1 = ws[OFF_WX + (size_t)(b0+bb1)*KWc + (s+1)*Wc + i1];
    }
    lds_barrier();   // h+x staging ready
    const u16* bBase = bF + (size_t)n16*40 + (size_t)quad*8;
    short8 bx[4];
    #pragma unroll
    for (int c=0;c<4;c++) bx[c] = *(const short8*)(bBase + (size_t)(5+c)*640);
    short8 bh[5];
    #pragma unroll
    for (int c=0;c<5;c++) bh[c] = *(const short8*)(bBase + (size_t)c*640);
    // ---- phase A: wih . x ----
    floatx4 acc[4] = {{0.f,0.f,0.f,0.f},{0.f,0.f,0.f,0.f},{0.f,0.f,0.f,0.f},{0.f,0.f,0.f,0.f}};
    #pragma unroll
    for (int ca=0;ca<4;ca++){
      #pragma unroll
      for (int ti=0;ti<4;ti++)
        acc[ti] = __builtin_amdgcn_mfma_f32_16x16x32_bf16(wihA[ti][ca], bx[ca], acc[ti], 0,0,0);
    }
    if (isN){
      if (n16 < 8){
        #pragma unroll
        for (int ti=0;ti<4;ti++){
          int tile = w*4 + ti;
          if (tile < 30){
            int srb = (tile - 20)*16 + quad*4;
            float* gq = g_np + srb*10 + n16;
            #pragma unroll
            for (int r=0;r<4;r++) gq[r*10] = acc[ti][r];
          }
        }
      }
      #pragma unroll
      for (int ti=0;ti<4;ti++) acc[ti] = (floatx4){0.f,0.f,0.f,0.f};
    }
    // ---- phase B: whh . h, 5 packed chunks (hi cols 0-7, lo cols 8-15) ----
    #pragma unroll
    for (int c=0;c<5;c++){
      #pragma unroll
      for (int ti=0;ti<4;ti++)
        acc[ti] = __builtin_amdgcn_mfma_f32_16x16x32_bf16(whhA[ti][c], bh[c], acc[ti], 0,0,0);
    }
    // dual-dump: hi partial (lanes 0-7, includes wih.x) and lo partial (lanes 8-15)
    #pragma unroll
    for (int ti=0;ti<4;ti++){
      int tile = w*4 + ti;
      if (tile < 30){
        int sec = tile/10;
        int srb = (tile - sec*10)*16 + quad*4;
        if (sec < 2){
          float* gp = g_rz + (sec*160 + srb)*17 + n16;
          #pragma unroll
          for (int r=0;r<4;r++) gp[r*17] = acc[ti][r];
        } else {
          float* gh = g_nh + srb*17 + n16;
          #pragma unroll
          for (int r=0;r<4;r++) gh[r*17] = acc[ti][r];
        }
      }
    }
    lds_barrier();   // gates ready; bF MFMA reads done
    #pragma unroll
    for (int q=0;q<3;q++){
      int task = tid + q*512;
      if (task < 1200){
        int t = task >> 3, bb = task & 7;
        float a_r = g_rz[t*17+bb] + g_rz[t*17+bb+8] + brz_r[q];
        float a_z = g_rz[(160+t)*17+bb] + g_rz[(160+t)*17+bb+8] + brz_z[q];
        float nhv = g_nh[t*17+bb] + g_nh[t*17+bb+8];
        float r  = 1.f/(1.f+__expf(-a_r));
        float zz = 1.f/(1.f+__expf(-a_z));
        float nx = (g_np[t*10+bb] + bnp_[q]) + r*(nhv + bnh_[q]);
        nx = fminf(fmaxf(nx,-15.f),15.f);
        float e2 = __expf(2.f*nx);
        float n = (e2-1.f)/(e2+1.f);
        float h = (1.f-zz)*n + zz*hst[q];
        hst[q] = h;
        u16 hi = f2us(h); float hif = us2f(hi); u16 lo = f2us(h - hif);
        bF[(t>>5)*640 + bb*40 + (t&31)] = hi;
        bF[(t>>5)*640 + (bb+8)*40 + (t&31)] = lo;
      }
    }
    if (s < Kc-1){
      bF[(5+(i0>>5))*640 + bb0*40 + (i0&31)] = f2us(xp0);
      if (v1ok) bF[(5+(i1>>5))*640 + bb1*40 + (i1&31)] = f2us(xp1);
    }
  }
  #pragma unroll
  for (int q=0;q<3;q++){
    int task = tid + q*512;
    if (task < 1200){
      int t = task >> 3, bb = task & 7;
      out[((size_t)(b0+bb)*Kc + kk)*Hc + t] = hst[q];
    }
  }
}

extern "C" void kernel_launch(void* const* d_in, const int* in_sizes, int n_in,
                              void* d_out, int out_size, void* d_ws, size_t ws_size,
                              hipStream_t stream){
  const float* x        = (const float*)d_in[0];
  const float* y        = (const float*)d_in[1];
  const float* z_noise  = (const float*)d_in[2];
  const float* lin_w    = (const float*)d_in[3];
  const float* lin_b    = (const float*)d_in[4];
  const float* a        = (const float*)d_in[5];
  const float* bias     = (const float*)d_in[6];
  const float* gl_wih   = (const float*)d_in[7];
  const float* gl_whh   = (const float*)d_in[8];
  const float* gl_bih   = (const float*)d_in[9];
  const float* gl_bhh   = (const float*)d_in[10];
  const float* mu_w     = (const float*)d_in[11];
  const float* mu_b     = (const float*)d_in[12];
  const float* std_w    = (const float*)d_in[13];
  const float* std_b    = (const float*)d_in[14];
  const float* net_wih  = (const float*)d_in[15];
  const float* net_whh  = (const float*)d_in[16];
  const float* net_bih  = (const float*)d_in[17];
  const float* net_bhh  = (const float*)d_in[18];
  float* ws = (float*)d_ws;
  float* out = (float*)d_out;

  wx_kernel<<<(Bc*KWc+255)/256, 256, 0, stream>>>(x, lin_w, lin_b, ws);
  attn_kernel<<<Bc*Kc, 256, 0, stream>>>(y, a, bias, ws);
  glproj_kernel<<<(Kc*Bc*H3c+255)/256, 256, 0, stream>>>(gl_wih, gl_bih, ws);
  glgru4_kernel<<<Bc, 1024, 0, stream>>>(gl_whh, gl_bhh, z_noise, mu_w, mu_b, std_w, std_b, ws);
  causes3_kernel<<<Kc*4, 512, 0, stream>>>(net_wih, net_whh, net_bih, net_bhh, ws, out);
}

// Round 16
// 434.409 us; speedup vs baseline: 1.2770x; 1.0083x over previous
//
#include <hip/hip_runtime.h>

#define Bc 32
#define Kc 64
#define Wc 100
#define Hc 150
#define H3c 450
#define KWc 6400
#define ALPHAc 0.2f
#define THRESc 0.0002f

typedef unsigned int u32;
typedef unsigned short u16;
typedef __attribute__((ext_vector_type(8))) short short8;   // 8 bf16
typedef __attribute__((ext_vector_type(4))) float floatx4;  // 4 f32 acc

// ---- ws layout (float offsets), 4.55 MB ----
#define OFF_WX      0u          // 204800  Wx (B,K,W) fp32
#define OFF_CS      204800u     // 2048    causesum (B,K)
#define OFF_GX      206848u     // 921600  gl proj (s,b,g)
#define OFF_HT      1128448u    // 4800    h_t (B,H)
#define OFF_Z       1133248u    // 4800    z (B,H)

__device__ __forceinline__ float us2f(u16 u){ u32 x=((u32)u)<<16; return __uint_as_float(x); }
__device__ __forceinline__ u16 f2us(float f){
  u32 x = __float_as_uint(f);
  u32 r = (x + 0x7fffu + ((x>>16)&1u)) >> 16;   // RNE bf16
  return (u16)r;
}

// LDS-only barrier: skips the vmcnt(0) drain __syncthreads would emit; global
// loads issued before it stay in flight (consumed via register deps).
__device__ __forceinline__ void lds_barrier(){
  __builtin_amdgcn_sched_barrier(0);
  asm volatile("s_waitcnt lgkmcnt(0)" ::: "memory");
  __builtin_amdgcn_s_barrier();
  __builtin_amdgcn_sched_barrier(0);
}

// ---------- Wx = x @ lin_w.T + lin_b ----------
__global__ void wx_kernel(const float* __restrict__ x, const float* __restrict__ lin_w,
                          const float* __restrict__ lin_b, float* __restrict__ ws){
  int o = blockIdx.x*256 + threadIdx.x;
  if (o >= Bc*KWc) return;
  int i = o % Wc;
  int bk = o / Wc;
  const float4* xr = (const float4*)(x + bk*Wc);
  const float4* wr = (const float4*)(lin_w + i*Wc);
  float acc = lin_b[i];
  #pragma unroll
  for (int j=0;j<25;j++){
    float4 xv = xr[j], wv = wr[j];
    acc += xv.x*wv.x + xv.y*wv.y + xv.z*wv.z + xv.w*wv.w;
  }
  ws[OFF_WX + o] = acc;
}

// ---------- attention softmax + thresholded sum (float4, __expf, log-threshold) ----------
__global__ void attn_kernel(const float* __restrict__ y, const float* __restrict__ a,
                            const float* __restrict__ bias, float* __restrict__ ws){
  __shared__ __align__(16) float e_l[KWc];
  __shared__ float red[4];
  int row = blockIdx.x;          // b*64 + k
  int b = row >> 6, k = row & 63;
  int tid = threadIdx.x;
  float a0 = a[0], a1 = a[1];
  float yv = y[row];
  const float4* v4  = (const float4*)(ws + OFF_WX + (size_t)b*KWc);
  const float4* br4 = (const float4*)(bias + (size_t)k*KWc);
  float4* e4 = (float4*)e_l;
  float ay = a0*yv;
  float m = -3.4e38f;
  for (int j=tid; j<KWc/4; j+=256){
    float4 vv = v4[j], bb = br4[j];
    float4 e;
    e.x = ay + a1*vv.x + bb.x; e.x = (e.x>=0.f)?e.x:ALPHAc*e.x;
    e.y = ay + a1*vv.y + bb.y; e.y = (e.y>=0.f)?e.y:ALPHAc*e.y;
    e.z = ay + a1*vv.z + bb.z; e.z = (e.z>=0.f)?e.z:ALPHAc*e.z;
    e.w = ay + a1*vv.w + bb.w; e.w = (e.w>=0.f)?e.w:ALPHAc*e.w;
    e4[j] = e;
    m = fmaxf(m, fmaxf(fmaxf(e.x,e.y), fmaxf(e.z,e.w)));
  }
  for (int o=32;o;o>>=1) m = fmaxf(m, __shfl_down(m, o));
  if ((tid&63)==0) red[tid>>6] = m;
  __syncthreads();
  m = fmaxf(fmaxf(red[0],red[1]), fmaxf(red[2],red[3]));
  __syncthreads();
  float ssum = 0.f;
  for (int j=tid; j<KWc/4; j+=256){
    float4 e = e4[j];
    ssum += __expf(e.x-m) + __expf(e.y-m) + __expf(e.z-m) + __expf(e.w-m);
  }
  for (int o=32;o;o>>=1) ssum += __shfl_down(ssum, o);
  if ((tid&63)==0) red[tid>>6] = ssum;
  __syncthreads();
  float s = red[0]+red[1]+red[2]+red[3];
  float thr = m + logf(THRESc * s);
  float cs = 0.f;
  for (int j=tid; j<KWc/4; j+=256){
    float4 e = e4[j];
    float4 vv = v4[j];
    if (e.x >= thr) cs += vv.x;
    if (e.y >= thr) cs += vv.y;
    if (e.z >= thr) cs += vv.z;
    if (e.w >= thr) cs += vv.w;
  }
  for (int o=32;o;o>>=1) cs += __shfl_down(cs, o);
  if ((tid&63)==0) red[tid>>6] = cs;
  __syncthreads();
  if (tid==0) ws[OFF_CS + row] = red[0]+red[1]+red[2]+red[3];
}

// ---------- gl input projection ----------
__global__ void glproj_kernel(const float* __restrict__ gl_wih, const float* __restrict__ gl_bih,
                              float* __restrict__ ws){
  int o = blockIdx.x*256 + threadIdx.x;
  if (o >= Kc*Bc*H3c) return;
  int g = o % H3c;
  int t = o / H3c;               // s*32 + b
  int b = t & 31, s = t >> 5;
  float cs = ws[OFF_CS + b*Kc + s];
  const float4* xr = (const float4*)(ws + OFF_WX + b*KWc + s*Wc);
  const float4* wr = (const float4*)(gl_wih + g*Wc);
  float acc = gl_bih[g];
  #pragma unroll
  for (int j=0;j<25;j++){
    float4 wv = wr[j], xv = xr[j];
    acc += (xv.x+cs)*wv.x + (xv.y+cs)*wv.y + (xv.z+cs)*wv.z + (xv.w+cs)*wv.w;
  }
  ws[OFF_GX + o] = acc;
}

// ---------- gl recurrent GRU v16: v15 + waves_per_eu(4,4) to kill wreg spill ----------
// Round-15 PMC: VGPR_Count=64 (= 512/8, the allocator's DEFAULT 8-waves/EU target),
// but wreg needs 76 -> whole weight array in scratch -> VALUBusy 1%, 198.8us.
// amdgpu_waves_per_eu(4,4) pins the target at actual residency (16 waves/block,
// 1 block/CU = 4/EU) -> 128-reg budget -> wreg promoted. Init made unconditional.
__global__ __attribute__((amdgpu_waves_per_eu(4,4))) void __launch_bounds__(1024,1)
glgru4_kernel(
    const float* __restrict__ gl_whh, const float* __restrict__ gl_bhh,
    const float* __restrict__ z_noise, const float* __restrict__ mu_w,
    const float* __restrict__ mu_b, const float* __restrict__ std_w,
    const float* __restrict__ std_b, float* __restrict__ ws){
  __shared__ __align__(16) float hbuf[2][152];    // f32 h, rows 150/151 stay 0
  __shared__ __align__(16) float dotb[2][3][152]; // [half][gate][t]
  int b = blockIdx.x;            // one batch per block
  int tid = threadIdx.x;
  bool dotter = (tid < 900);
  int half = (tid >= 450) ? 1 : 0;
  int row  = dotter ? (tid - half*450) : 0;   // 0..449 = g*150+t (0 for tails: harmless)
  int g = row/150, t = row - g*150;

  // unconditional init (tail threads load row 0 half 1 = in-bounds, values unused)
  float wreg[76];
  {
    const float* wr = gl_whh + (size_t)row*Hc + half*76;
    #pragma unroll
    for (int i=0;i<37;i++){
      float2 v = *(const float2*)(wr + 2*i);
      wreg[2*i] = v.x; wreg[2*i+1] = v.y;
    }
    if (!half){ float2 v = *(const float2*)(wr + 74); wreg[74]=v.x; wreg[75]=v.y; }
    else      { wreg[74]=0.f; wreg[75]=0.f; }
  }
  if (tid < 152){ hbuf[0][tid] = 0.f; hbuf[1][tid] = 0.f; }

  float bh_r=0.f, bh_z=0.f, bh_n=0.f, hreg=0.f;
  if (tid < Hc){
    bh_r = gl_bhh[tid]; bh_z = gl_bhh[Hc+tid]; bh_n = gl_bhh[2*Hc+tid];
  }
  __syncthreads();

  for (int s=0;s<Kc;s++){
    int rb = s & 1;
    float gxr=0.f, gxz=0.f, gxn=0.f;
    if (tid < Hc){
      const float* gp = ws + OFF_GX + (size_t)(s*Bc + b)*H3c;
      gxr = gp[tid]; gxz = gp[Hc+tid]; gxn = gp[2*Hc+tid];
    }
    if (dotter){
      const float* hb = &hbuf[rb][half*76];
      float a0=0.f,a1=0.f,a2=0.f,a3=0.f;
      #pragma unroll
      for (int i=0;i<19;i++){
        float4 h4 = *(const float4*)(hb + 4*i);
        a0 += wreg[4*i]  *h4.x;
        a1 += wreg[4*i+1]*h4.y;
        a2 += wreg[4*i+2]*h4.z;
        a3 += wreg[4*i+3]*h4.w;
      }
      dotb[half][g][t] = (a0+a1)+(a2+a3);
    }
    lds_barrier();   // dots ready
    if (tid < Hc){
      float dr = dotb[0][0][tid] + dotb[1][0][tid];
      float dz = dotb[0][1][tid] + dotb[1][1][tid];
      float dn = dotb[0][2][tid] + dotb[1][2][tid];
      float a_r = gxr + dr + bh_r;
      float a_z = gxz + dz + bh_z;
      float rr = 1.f/(1.f+__expf(-a_r));
      float zz = 1.f/(1.f+__expf(-a_z));
      float nx = gxn + rr*(dn + bh_n);
      nx = fminf(fmaxf(nx,-15.f),15.f);
      float e2 = __expf(2.f*nx);
      float n = (e2-1.f)/(e2+1.f);
      float h = (1.f-zz)*n + zz*hreg;
      hreg = h;
      hbuf[rb^1][tid] = h;
    }
    lds_barrier();   // h ready; dotb consumed (WAR safe)
  }
  if (tid < Hc) ws[OFF_HT + (size_t)b*Hc + tid] = hreg;

  // ---- fused z = mu + exp(0.5*log_var)*noise ----
  if (tid < 300){
    int which = tid/150, tt = tid - which*150;
    const float* wrow = (which ? std_w : mu_w) + (size_t)tt*Hc;
    float acc = which ? std_b[tt] : mu_b[tt];
    const float* hb = hbuf[0];
    #pragma unroll
    for (int i=0;i<75;i++){
      float2 wv = *(const float2*)(wrow + 2*i);
      float2 hv = *(const float2*)(hb + 2*i);
      acc += wv.x*hv.x + wv.y*hv.y;
    }
    dotb[0][which][tt] = acc;
  }
  lds_barrier();
  if (tid < Hc){
    float mu = dotb[0][0][tid], lv = dotb[0][1][tid];
    float sg = expf(0.5f*lv);
    ws[OFF_Z + (size_t)b*Hc + tid] = mu + sg*z_noise[(size_t)b*Hc + tid];
  }
}

// ---------- causes v15: v14 + waves_per_eu(2,2) -> 256-reg budget, kill in-loop spill ----------
// 512 thr = 8 waves = 2 waves/SIMD resident; default allocator target was 4/EU (128
// regs) -> chronic ~36-60MB scratch spill. (2,2) grants the full 256-reg budget.
__global__ __attribute__((amdgpu_waves_per_eu(2,2))) void __launch_bounds__(512,1)
causes3_kernel(
    const float* __restrict__ net_wih, const float* __restrict__ net_whh,
    const float* __restrict__ net_bih, const float* __restrict__ net_bhh,
    const float* __restrict__ ws, float* __restrict__ out){
  __shared__ __align__(16) u16 bF[9*16*40];    // h: 5 chunks packed; x: 4 chunks
  __shared__ float g_rz[320*17];               // [row][16 lanes], stride 17
  __shared__ float g_nh[160*17];
  __shared__ float g_np[160*10];
  int kk = blockIdx.x & 63, bg = blockIdx.x >> 6, b0 = bg*8;
  int tid = threadIdx.x;
  int w = tid >> 6, lane = tid & 63, quad = lane >> 4, n16 = lane & 15;
  const float* whhk = net_whh + (size_t)kk*H3c*Hc;
  const float* wihk = net_wih + (size_t)kk*H3c*Wc;
  const float* bihk = net_bih + kk*H3c;
  const float* bhhk = net_bhh + kk*H3c;

  short8 whhA[4][5], wihA[4][4];
  #pragma unroll
  for (int ti=0; ti<4; ti++){
    int tile = w*4 + ti;
    int sec = tile/10;
    int sr = (tile - sec*10)*16 + n16;
    bool rowok = (tile < 30) && (sr < Hc);
    int grow = (sec<3 ? sec : 2)*Hc + sr;
    const float* wr = whhk + (size_t)grow*Hc;     // 600B stride: 8B-aligned
    #pragma unroll
    for (int c=0;c<5;c++){
      union { short8 v; u16 u[8]; } t8;
      #pragma unroll
      for (int j2=0;j2<4;j2++){
        int kk2 = c*32 + quad*8 + j2*2;
        float2 wv = (rowok && (kk2+1) < Hc) ? *(const float2*)(wr + kk2) : make_float2(0.f,0.f);
        t8.u[j2*2]   = f2us(wv.x);
        t8.u[j2*2+1] = f2us(wv.y);
      }
      whhA[ti][c] = t8.v;
    }
    const float* wr2 = wihk + (size_t)grow*Wc;    // 400B stride: 16B-aligned
    #pragma unroll
    for (int c=0;c<4;c++){
      union { short8 v; u16 u[8]; } t8;
      #pragma unroll
      for (int j4=0;j4<2;j4++){
        int kb = c*32 + quad*8 + j4*4;            // mult of 4 -> 16B-aligned
        float4 wv = (rowok && kb < Wc) ? *(const float4*)(wr2 + kb) : make_float4(0.f,0.f,0.f,0.f);
        t8.u[j4*4]   = f2us(wv.x);
        t8.u[j4*4+1] = f2us(wv.y);
        t8.u[j4*4+2] = f2us(wv.z);
        t8.u[j4*4+3] = f2us(wv.w);
      }
      wihA[ti][c] = t8.v;
    }
  }

  for (int i=tid; i<9*16*40/2; i+=512) ((u32*)bF)[i] = 0u;

  float hst[3] = {0.f,0.f,0.f};
  float brz_r[3], brz_z[3], bnh_[3], bnp_[3];
  #pragma unroll
  for (int q=0;q<3;q++){
    int task = tid + q*512;
    if (task < 1200){
      int t = task >> 3, bb = task & 7;
      float h = ws[OFF_Z + (b0+bb)*Hc + t];
      hst[q] = h;
      brz_r[q] = bhhk[t]      + bihk[t];
      brz_z[q] = bhhk[Hc+t]   + bihk[Hc+t];
      bnh_[q]  = bhhk[2*Hc+t];
      bnp_[q]  = bihk[2*Hc+t];
      u16 hi = f2us(h); float hif = us2f(hi); u16 lo = f2us(h - hif);
      bF[(t>>5)*640 + bb*40 + (t&31)] = hi;
      bF[(t>>5)*640 + (bb+8)*40 + (t&31)] = lo;
    }
  }
  for (int it=tid; it<800; it+=512){
    int bb = it/100, i = it - bb*100;
    float xv = ws[OFF_WX + (b0+bb)*KWc + i];
    bF[(5+(i>>5))*640 + bb*40 + (i&31)] = f2us(xv);
  }

  int bb0 = tid/100, i0 = tid - bb0*100;
  int it1 = tid + 512;
  int bb1 = it1/100, i1 = it1 - bb1*100;
  bool v1ok = (it1 < 800);

  const bool isN = (w >= 5);
  for (int s=0;s<Kc;s++){
    float xp0 = 0.f, xp1 = 0.f;
    if (s < Kc-1){
      xp0 = ws[OFF_WX + (size_t)(b0+bb0)*KWc + (s+1)*Wc + i0];
      if (v1ok) xp1 = ws[OFF_WX + (size_t)(b0+bb1)*KWc + (s+1)*Wc + i1];
    }
    lds_barrier();   // h+x staging ready
    const u16* bBase = bF + (size_t)n16*40 + (size_t)quad*8;
    short8 bx[4];
    #pragma unroll
    for (int c=0;c<4;c++) bx[c] = *(const short8*)(bBase + (size_t)(5+c)*640);
    short8 bh[5];
    #pragma unroll
    for (int c=0;c<5;c++) bh[c] = *(const short8*)(bBase + (size_t)c*640);
    // ---- phase A: wih . x ----
    floatx4 acc[4] = {{0.f,0.f,0.f,0.f},{0.f,0.f,0.f,0.f},{0.f,0.f,0.f,0.f},{0.f,0.f,0.f,0.f}};
    #pragma unroll
    for (int ca=0;ca<4;ca++){
      #pragma unroll
      for (int ti=0;ti<4;ti++)
        acc[ti] = __builtin_amdgcn_mfma_f32_16x16x32_bf16(wihA[ti][ca], bx[ca], acc[ti], 0,0,0);
    }
    if (isN){
      if (n16 < 8){
        #pragma unroll
        for (int ti=0;ti<4;ti++){
          int tile = w*4 + ti;
          if (tile < 30){
            int srb = (tile - 20)*16 + quad*4;
            float* gq = g_np + srb*10 + n16;
            #pragma unroll
            for (int r=0;r<4;r++) gq[r*10] = acc[ti][r];
          }
        }
      }
      #pragma unroll
      for (int ti=0;ti<4;ti++) acc[ti] = (floatx4){0.f,0.f,0.f,0.f};
    }
    // ---- phase B: whh . h, 5 packed chunks (hi cols 0-7, lo cols 8-15) ----
    #pragma unroll
    for (int c=0;c<5;c++){
      #pragma unroll
      for (int ti=0;ti<4;ti++)
        acc[ti] = __builtin_amdgcn_mfma_f32_16x16x32_bf16(whhA[ti][c], bh[c], acc[ti], 0,0,0);
    }
    // dual-dump: hi partial (lanes 0-7, includes wih.x) and lo partial (lanes 8-15)
    #pragma unroll
    for (int ti=0;ti<4;ti++){
      int tile = w*4 + ti;
      if (tile < 30){
        int sec = tile/10;
        int srb = (tile - sec*10)*16 + quad*4;
        if (sec < 2){
          float* gp = g_rz + (sec*160 + srb)*17 + n16;
          #pragma unroll
          for (int r=0;r<4;r++) gp[r*17] = acc[ti][r];
        } else {
          float* gh = g_nh + srb*17 + n16;
          #pragma unroll
          for (int r=0;r<4;r++) gh[r*17] = acc[ti][r];
        }
      }
    }
    lds_barrier();   // gates ready; bF MFMA reads done
    #pragma unroll
    for (int q=0;q<3;q++){
      int task = tid + q*512;
      if (task < 1200){
        int t = task >> 3, bb = task & 7;
        float a_r = g_rz[t*17+bb] + g_rz[t*17+bb+8] + brz_r[q];
        float a_z = g_rz[(160+t)*17+bb] + g_rz[(160+t)*17+bb+8] + brz_z[q];
        float nhv = g_nh[t*17+bb] + g_nh[t*17+bb+8];
        float r  = 1.f/(1.f+__expf(-a_r));
        float zz = 1.f/(1.f+__expf(-a_z));
        float nx = (g_np[t*10+bb] + bnp_[q]) + r*(nhv + bnh_[q]);
        nx = fminf(fmaxf(nx,-15.f),15.f);
        float e2 = __expf(2.f*nx);
        float n = (e2-1.f)/(e2+1.f);
        float h = (1.f-zz)*n + zz*hst[q];
        hst[q] = h;
        u16 hi = f2us(h); float hif = us2f(hi); u16 lo = f2us(h - hif);
        bF[(t>>5)*640 + bb*40 + (t&31)] = hi;
        bF[(t>>5)*640 + (bb+8)*40 + (t&31)] = lo;
      }
    }
    if (s < Kc-1){
      bF[(5+(i0>>5))*640 + bb0*40 + (i0&31)] = f2us(xp0);
      if (v1ok) bF[(5+(i1>>5))*640 + bb1*40 + (i1&31)] = f2us(xp1);
    }
  }
  #pragma unroll
  for (int q=0;q<3;q++){
    int task = tid + q*512;
    if (task < 1200){
      int t = task >> 3, bb = task & 7;
      out[((size_t)(b0+bb)*Kc + kk)*Hc + t] = hst[q];
    }
  }
}

extern "C" void kernel_launch(void* const* d_in, const int* in_sizes, int n_in,
                              void* d_out, int out_size, void* d_ws, size_t ws_size,
                              hipStream_t stream){
  const float* x        = (const float*)d_in[0];
  const float* y        = (const float*)d_in[1];
  const float* z_noise  = (const float*)d_in[2];
  const float* lin_w    = (const float*)d_in[3];
  const float* lin_b    = (const float*)d_in[4];
  const float* a        = (const float*)d_in[5];
  const float* bias     = (const float*)d_in[6];
  const float* gl_wih   = (const float*)d_in[7];
  const float* gl_whh   = (const float*)d_in[8];
  const float* gl_bih   = (const float*)d_in[9];
  const float* gl_bhh   = (const float*)d_in[10];
  const float* mu_w     = (const float*)d_in[11];
  const float* mu_b     = (const float*)d_in[12];
  const float* std_w    = (const float*)d_in[13];
  const float* std_b    = (const float*)d_in[14];
  const float* net_wih  = (const float*)d_in[15];
  const float* net_whh  = (const float*)d_in[16];
  const float* net_bih  = (const float*)d_in[17];
  const float* net_bhh  = (const float*)d_in[18];
  float* ws = (float*)d_ws;
  float* out = (float*)d_out;

  wx_kernel<<<(Bc*KWc+255)/256, 256, 0, stream>>>(x, lin_w, lin_b, ws);
  attn_kernel<<<Bc*Kc, 256, 0, stream>>>(y, a, bias, ws);
  glproj_kernel<<<(Kc*Bc*H3c+255)/256, 256, 0, stream>>>(gl_wih, gl_bih, ws);
  glgru4_kernel<<<Bc, 1024, 0, stream>>>(gl_whh, gl_bhh, z_noise, mu_w, mu_b, std_w, std_b, ws);
  causes3_kernel<<<Kc*4, 512, 0, stream>>>(net_wih, net_whh, net_bih, net_bhh, ws, out);
}

// Round 17
// 422.058 us; speedup vs baseline: 1.3144x; 1.0293x over previous
//
#include <hip/hip_runtime.h>

#define Bc 32
#define Kc 64
#define Wc 100
#define Hc 150
#define H3c 450
#define KWc 6400
#define ALPHAc 0.2f
#define THRESc 0.0002f

typedef unsigned int u32;
typedef unsigned short u16;
typedef __attribute__((ext_vector_type(8))) short short8;   // 8 bf16
typedef __attribute__((ext_vector_type(4))) float floatx4;  // 4 f32 acc

// ---- ws layout (float offsets), 4.55 MB ----
#define OFF_WX      0u          // 204800  Wx (B,K,W) fp32
#define OFF_CS      204800u     // 2048    causesum (B,K)
#define OFF_GX      206848u     // 921600  gl proj (s,b,g)
#define OFF_HT      1128448u    // 4800    h_t (B,H)
#define OFF_Z       1133248u    // 4800    z (B,H)

__device__ __forceinline__ float us2f(u16 u){ u32 x=((u32)u)<<16; return __uint_as_float(x); }
__device__ __forceinline__ u16 f2us(float f){
  u32 x = __float_as_uint(f);
  u32 r = (x + 0x7fffu + ((x>>16)&1u)) >> 16;   // RNE bf16
  return (u16)r;
}

// LDS-only barrier: skips the vmcnt(0) drain __syncthreads would emit; global
// loads issued before it stay in flight (consumed via register deps).
__device__ __forceinline__ void lds_barrier(){
  __builtin_amdgcn_sched_barrier(0);
  asm volatile("s_waitcnt lgkmcnt(0)" ::: "memory");
  __builtin_amdgcn_s_barrier();
  __builtin_amdgcn_sched_barrier(0);
}

// ---------- Wx = x @ lin_w.T + lin_b ----------
__global__ void wx_kernel(const float* __restrict__ x, const float* __restrict__ lin_w,
                          const float* __restrict__ lin_b, float* __restrict__ ws){
  int o = blockIdx.x*256 + threadIdx.x;
  if (o >= Bc*KWc) return;
  int i = o % Wc;
  int bk = o / Wc;
  const float4* xr = (const float4*)(x + bk*Wc);
  const float4* wr = (const float4*)(lin_w + i*Wc);
  float acc = lin_b[i];
  #pragma unroll
  for (int j=0;j<25;j++){
    float4 xv = xr[j], wv = wr[j];
    acc += xv.x*wv.x + xv.y*wv.y + xv.z*wv.z + xv.w*wv.w;
  }
  ws[OFF_WX + o] = acc;
}

// ---------- attention softmax + thresholded sum (float4, __expf, log-threshold) ----------
__global__ void attn_kernel(const float* __restrict__ y, const float* __restrict__ a,
                            const float* __restrict__ bias, float* __restrict__ ws){
  __shared__ __align__(16) float e_l[KWc];
  __shared__ float red[4];
  int row = blockIdx.x;          // b*64 + k
  int b = row >> 6, k = row & 63;
  int tid = threadIdx.x;
  float a0 = a[0], a1 = a[1];
  float yv = y[row];
  const float4* v4  = (const float4*)(ws + OFF_WX + (size_t)b*KWc);
  const float4* br4 = (const float4*)(bias + (size_t)k*KWc);
  float4* e4 = (float4*)e_l;
  float ay = a0*yv;
  float m = -3.4e38f;
  for (int j=tid; j<KWc/4; j+=256){
    float4 vv = v4[j], bb = br4[j];
    float4 e;
    e.x = ay + a1*vv.x + bb.x; e.x = (e.x>=0.f)?e.x:ALPHAc*e.x;
    e.y = ay + a1*vv.y + bb.y; e.y = (e.y>=0.f)?e.y:ALPHAc*e.y;
    e.z = ay + a1*vv.z + bb.z; e.z = (e.z>=0.f)?e.z:ALPHAc*e.z;
    e.w = ay + a1*vv.w + bb.w; e.w = (e.w>=0.f)?e.w:ALPHAc*e.w;
    e4[j] = e;
    m = fmaxf(m, fmaxf(fmaxf(e.x,e.y), fmaxf(e.z,e.w)));
  }
  for (int o=32;o;o>>=1) m = fmaxf(m, __shfl_down(m, o));
  if ((tid&63)==0) red[tid>>6] = m;
  __syncthreads();
  m = fmaxf(fmaxf(red[0],red[1]), fmaxf(red[2],red[3]));
  __syncthreads();
  float ssum = 0.f;
  for (int j=tid; j<KWc/4; j+=256){
    float4 e = e4[j];
    ssum += __expf(e.x-m) + __expf(e.y-m) + __expf(e.z-m) + __expf(e.w-m);
  }
  for (int o=32;o;o>>=1) ssum += __shfl_down(ssum, o);
  if ((tid&63)==0) red[tid>>6] = ssum;
  __syncthreads();
  float s = red[0]+red[1]+red[2]+red[3];
  float thr = m + logf(THRESc * s);
  float cs = 0.f;
  for (int j=tid; j<KWc/4; j+=256){
    float4 e = e4[j];
    float4 vv = v4[j];
    if (e.x >= thr) cs += vv.x;
    if (e.y >= thr) cs += vv.y;
    if (e.z >= thr) cs += vv.z;
    if (e.w >= thr) cs += vv.w;
  }
  for (int o=32;o;o>>=1) cs += __shfl_down(cs, o);
  if ((tid&63)==0) red[tid>>6] = cs;
  __syncthreads();
  if (tid==0) ws[OFF_CS + row] = red[0]+red[1]+red[2]+red[3];
}

// ---------- gl input projection ----------
__global__ void glproj_kernel(const float* __restrict__ gl_wih, const float* __restrict__ gl_bih,
                              float* __restrict__ ws){
  int o = blockIdx.x*256 + threadIdx.x;
  if (o >= Kc*Bc*H3c) return;
  int g = o % H3c;
  int t = o / H3c;               // s*32 + b
  int b = t & 31, s = t >> 5;
  float cs = ws[OFF_CS + b*Kc + s];
  const float4* xr = (const float4*)(ws + OFF_WX + b*KWc + s*Wc);
  const float4* wr = (const float4*)(gl_wih + g*Wc);
  float acc = gl_bih[g];
  #pragma unroll
  for (int j=0;j<25;j++){
    float4 wv = wr[j], xv = xr[j];
    acc += (xv.x+cs)*wv.x + (xv.y+cs)*wv.y + (xv.z+cs)*wv.z + (xv.w+cs)*wv.w;
  }
  ws[OFF_GX + o] = acc;
}

// ---------- gl recurrent GRU v17: bf16-packed reg weights (38 u32 < 64-reg budget) ----------
// Round-16 lesson: __launch_bounds__ itself emits amdgpu_waves_per_eu and CONFLICTS
// with an explicit attribute -> allocator kept its 8-waves/EU default (64 regs) and
// wreg[76] f32 stayed in scratch (VALUBusy 1%). Two fixes: (a) pack weights as bf16
// pairs -> 38 u32 regs, fits even a 64-reg budget; (b) clean single attribute
// (no __launch_bounds__) requesting 4 waves/EU -> 128-reg budget.
__global__ void __attribute__((amdgpu_flat_work_group_size(1024,1024), amdgpu_waves_per_eu(4,4)))
glgru4_kernel(
    const float* __restrict__ gl_whh, const float* __restrict__ gl_bhh,
    const float* __restrict__ z_noise, const float* __restrict__ mu_w,
    const float* __restrict__ mu_b, const float* __restrict__ std_w,
    const float* __restrict__ std_b, float* __restrict__ ws){
  __shared__ __align__(16) float hbuf[2][152];    // f32 h, rows 150/151 stay 0
  __shared__ __align__(16) float dotb[2][3][152]; // [half][gate][t]
  int b = blockIdx.x;            // one batch per block
  int tid = threadIdx.x;
  bool dotter = (tid < 900);
  int half = (tid >= 450) ? 1 : 0;
  int row  = dotter ? (tid - half*450) : 0;   // 0..449 = g*150+t (0 for tails: harmless)
  int g = row/150, t = row - g*150;

  // bf16-packed half-row: 38 u32 (76 weights). half1 covers k=76..149 (37 pairs) + zero pad.
  u32 wp[38];
  {
    const float* wr = gl_whh + (size_t)row*Hc + half*76;
    #pragma unroll
    for (int i=0;i<37;i++){
      float2 v = *(const float2*)(wr + 2*i);
      wp[i] = (u32)f2us(v.x) | ((u32)f2us(v.y) << 16);
    }
    if (!half){ float2 v = *(const float2*)(wr + 74); wp[37] = (u32)f2us(v.x) | ((u32)f2us(v.y) << 16); }
    else      { wp[37] = 0u; }
  }
  if (tid < 152){ hbuf[0][tid] = 0.f; hbuf[1][tid] = 0.f; }

  float bh_r=0.f, bh_z=0.f, bh_n=0.f, hreg=0.f;
  if (tid < Hc){
    bh_r = gl_bhh[tid]; bh_z = gl_bhh[Hc+tid]; bh_n = gl_bhh[2*Hc+tid];
  }
  __syncthreads();

  for (int s=0;s<Kc;s++){
    int rb = s & 1;
    float gxr=0.f, gxz=0.f, gxn=0.f;
    if (tid < Hc){
      const float* gp = ws + OFF_GX + (size_t)(s*Bc + b)*H3c;
      gxr = gp[tid]; gxz = gp[Hc+tid]; gxn = gp[2*Hc+tid];
    }
    if (dotter){
      const float* hb = &hbuf[rb][half*76];
      float a0=0.f, a1=0.f;
      #pragma unroll
      for (int i=0;i<19;i++){
        float4 h4 = *(const float4*)(hb + 4*i);
        u32 u0 = wp[2*i], u1 = wp[2*i+1];
        a0 += __uint_as_float(u0<<16)        *h4.x;
        a1 += __uint_as_float(u0&0xffff0000u)*h4.y;
        a0 += __uint_as_float(u1<<16)        *h4.z;
        a1 += __uint_as_float(u1&0xffff0000u)*h4.w;
      }
      dotb[half][g][t] = a0 + a1;
    }
    lds_barrier();   // dots ready
    if (tid < Hc){
      float dr = dotb[0][0][tid] + dotb[1][0][tid];
      float dz = dotb[0][1][tid] + dotb[1][1][tid];
      float dn = dotb[0][2][tid] + dotb[1][2][tid];
      float a_r = gxr + dr + bh_r;
      float a_z = gxz + dz + bh_z;
      float rr = 1.f/(1.f+__expf(-a_r));
      float zz = 1.f/(1.f+__expf(-a_z));
      float nx = gxn + rr*(dn + bh_n);
      nx = fminf(fmaxf(nx,-15.f),15.f);
      float e2 = __expf(2.f*nx);
      float n = (e2-1.f)/(e2+1.f);
      float h = (1.f-zz)*n + zz*hreg;
      hreg = h;
      hbuf[rb^1][tid] = h;
    }
    lds_barrier();   // h ready; dotb consumed (WAR safe)
  }
  if (tid < Hc) ws[OFF_HT + (size_t)b*Hc + tid] = hreg;

  // ---- fused z = mu + exp(0.5*log_var)*noise ----
  if (tid < 300){
    int which = tid/150, tt = tid - which*150;
    const float* wrow = (which ? std_w : mu_w) + (size_t)tt*Hc;
    float acc = which ? std_b[tt] : mu_b[tt];
    const float* hb = hbuf[0];
    #pragma unroll
    for (int i=0;i<75;i++){
      float2 wv = *(const float2*)(wrow + 2*i);
      float2 hv = *(const float2*)(hb + 2*i);
      acc += wv.x*hv.x + wv.y*hv.y;
    }
    dotb[0][which][tt] = acc;
  }
  lds_barrier();
  if (tid < Hc){
    float mu = dotb[0][0][tid], lv = dotb[0][1][tid];
    float sg = expf(0.5f*lv);
    ws[OFF_Z + (size_t)b*Hc + tid] = mu + sg*z_noise[(size_t)b*Hc + tid];
  }
}

// ---------- causes v16: v14 body + clean waves_per_eu(2,2) (no launch_bounds conflict) ----------
// 512 thr = 8 waves = 2 waves/SIMD resident; (2,2) alone (no conflicting
// __launch_bounds__ attr) should grant the 256-reg budget and kill the spill.
__global__ void __attribute__((amdgpu_flat_work_group_size(512,512), amdgpu_waves_per_eu(2,2)))
causes3_kernel(
    const float* __restrict__ net_wih, const float* __restrict__ net_whh,
    const float* __restrict__ net_bih, const float* __restrict__ net_bhh,
    const float* __restrict__ ws, float* __restrict__ out){
  __shared__ __align__(16) u16 bF[9*16*40];    // h: 5 chunks packed; x: 4 chunks
  __shared__ float g_rz[320*17];               // [row][16 lanes], stride 17
  __shared__ float g_nh[160*17];
  __shared__ float g_np[160*10];
  int kk = blockIdx.x & 63, bg = blockIdx.x >> 6, b0 = bg*8;
  int tid = threadIdx.x;
  int w = tid >> 6, lane = tid & 63, quad = lane >> 4, n16 = lane & 15;
  const float* whhk = net_whh + (size_t)kk*H3c*Hc;
  const float* wihk = net_wih + (size_t)kk*H3c*Wc;
  const float* bihk = net_bih + kk*H3c;
  const float* bhhk = net_bhh + kk*H3c;

  short8 whhA[4][5], wihA[4][4];
  #pragma unroll
  for (int ti=0; ti<4; ti++){
    int tile = w*4 + ti;
    int sec = tile/10;
    int sr = (tile - sec*10)*16 + n16;
    bool rowok = (tile < 30) && (sr < Hc);
    int grow = (sec<3 ? sec : 2)*Hc + sr;
    const float* wr = whhk + (size_t)grow*Hc;     // 600B stride: 8B-aligned
    #pragma unroll
    for (int c=0;c<5;c++){
      union { short8 v; u16 u[8]; } t8;
      #pragma unroll
      for (int j2=0;j2<4;j2++){
        int kk2 = c*32 + quad*8 + j2*2;
        float2 wv = (rowok && (kk2+1) < Hc) ? *(const float2*)(wr + kk2) : make_float2(0.f,0.f);
        t8.u[j2*2]   = f2us(wv.x);
        t8.u[j2*2+1] = f2us(wv.y);
      }
      whhA[ti][c] = t8.v;
    }
    const float* wr2 = wihk + (size_t)grow*Wc;    // 400B stride: 16B-aligned
    #pragma unroll
    for (int c=0;c<4;c++){
      union { short8 v; u16 u[8]; } t8;
      #pragma unroll
      for (int j4=0;j4<2;j4++){
        int kb = c*32 + quad*8 + j4*4;            // mult of 4 -> 16B-aligned
        float4 wv = (rowok && kb < Wc) ? *(const float4*)(wr2 + kb) : make_float4(0.f,0.f,0.f,0.f);
        t8.u[j4*4]   = f2us(wv.x);
        t8.u[j4*4+1] = f2us(wv.y);
        t8.u[j4*4+2] = f2us(wv.z);
        t8.u[j4*4+3] = f2us(wv.w);
      }
      wihA[ti][c] = t8.v;
    }
  }

  for (int i=tid; i<9*16*40/2; i+=512) ((u32*)bF)[i] = 0u;

  float hst[3] = {0.f,0.f,0.f};
  float brz_r[3], brz_z[3], bnh_[3], bnp_[3];
  #pragma unroll
  for (int q=0;q<3;q++){
    int task = tid + q*512;
    if (task < 1200){
      int t = task >> 3, bb = task & 7;
      float h = ws[OFF_Z + (b0+bb)*Hc + t];
      hst[q] = h;
      brz_r[q] = bhhk[t]      + bihk[t];
      brz_z[q] = bhhk[Hc+t]   + bihk[Hc+t];
      bnh_[q]  = bhhk[2*Hc+t];
      bnp_[q]  = bihk[2*Hc+t];
      u16 hi = f2us(h); float hif = us2f(hi); u16 lo = f2us(h - hif);
      bF[(t>>5)*640 + bb*40 + (t&31)] = hi;
      bF[(t>>5)*640 + (bb+8)*40 + (t&31)] = lo;
    }
  }
  for (int it=tid; it<800; it+=512){
    int bb = it/100, i = it - bb*100;
    float xv = ws[OFF_WX + (b0+bb)*KWc + i];
    bF[(5+(i>>5))*640 + bb*40 + (i&31)] = f2us(xv);
  }

  int bb0 = tid/100, i0 = tid - bb0*100;
  int it1 = tid + 512;
  int bb1 = it1/100, i1 = it1 - bb1*100;
  bool v1ok = (it1 < 800);

  const bool isN = (w >= 5);
  for (int s=0;s<Kc;s++){
    float xp0 = 0.f, xp1 = 0.f;
    if (s < Kc-1){
      xp0 = ws[OFF_WX + (size_t)(b0+bb0)*KWc + (s+1)*Wc + i0];
      if (v1ok) xp1 = ws[OFF_WX + (size_t)(b0+bb1)*KWc + (s+1)*Wc + i1];
    }
    lds_barrier();   // h+x staging ready
    const u16* bBase = bF + (size_t)n16*40 + (size_t)quad*8;
    short8 bx[4];
    #pragma unroll
    for (int c=0;c<4;c++) bx[c] = *(const short8*)(bBase + (size_t)(5+c)*640);
    short8 bh[5];
    #pragma unroll
    for (int c=0;c<5;c++) bh[c] = *(const short8*)(bBase + (size_t)c*640);
    // ---- phase A: wih . x ----
    floatx4 acc[4] = {{0.f,0.f,0.f,0.f},{0.f,0.f,0.f,0.f},{0.f,0.f,0.f,0.f},{0.f,0.f,0.f,0.f}};
    #pragma unroll
    for (int ca=0;ca<4;ca++){
      #pragma unroll
      for (int ti=0;ti<4;ti++)
        acc[ti] = __builtin_amdgcn_mfma_f32_16x16x32_bf16(wihA[ti][ca], bx[ca], acc[ti], 0,0,0);
    }
    if (isN){
      if (n16 < 8){
        #pragma unroll
        for (int ti=0;ti<4;ti++){
          int tile = w*4 + ti;
          if (tile < 30){
            int srb = (tile - 20)*16 + quad*4;
            float* gq = g_np + srb*10 + n16;
            #pragma unroll
            for (int r=0;r<4;r++) gq[r*10] = acc[ti][r];
          }
        }
      }
      #pragma unroll
      for (int ti=0;ti<4;ti++) acc[ti] = (floatx4){0.f,0.f,0.f,0.f};
    }
    // ---- phase B: whh . h, 5 packed chunks (hi cols 0-7, lo cols 8-15) ----
    #pragma unroll
    for (int c=0;c<5;c++){
      #pragma unroll
      for (int ti=0;ti<4;ti++)
        acc[ti] = __builtin_amdgcn_mfma_f32_16x16x32_bf16(whhA[ti][c], bh[c], acc[ti], 0,0,0);
    }
    // dual-dump: hi partial (lanes 0-7, includes wih.x) and lo partial (lanes 8-15)
    #pragma unroll
    for (int ti=0;ti<4;ti++){
      int tile = w*4 + ti;
      if (tile < 30){
        int sec = tile/10;
        int srb = (tile - sec*10)*16 + quad*4;
        if (sec < 2){
          float* gp = g_rz + (sec*160 + srb)*17 + n16;
          #pragma unroll
          for (int r=0;r<4;r++) gp[r*17] = acc[ti][r];
        } else {
          float* gh = g_nh + srb*17 + n16;
          #pragma unroll
          for (int r=0;r<4;r++) gh[r*17] = acc[ti][r];
        }
      }
    }
    lds_barrier();   // gates ready; bF MFMA reads done
    #pragma unroll
    for (int q=0;q<3;q++){
      int task = tid + q*512;
      if (task < 1200){
        int t = task >> 3, bb = task & 7;
        float a_r = g_rz[t*17+bb] + g_rz[t*17+bb+8] + brz_r[q];
        float a_z = g_rz[(160+t)*17+bb] + g_rz[(160+t)*17+bb+8] + brz_z[q];
        float nhv = g_nh[t*17+bb] + g_nh[t*17+bb+8];
        float r  = 1.f/(1.f+__expf(-a_r));
        float zz = 1.f/(1.f+__expf(-a_z));
        float nx = (g_np[t*10+bb] + bnp_[q]) + r*(nhv + bnh_[q]);
        nx = fminf(fmaxf(nx,-15.f),15.f);
        float e2 = __expf(2.f*nx);
        float n = (e2-1.f)/(e2+1.f);
        float h = (1.f-zz)*n + zz*hst[q];
        hst[q] = h;
        u16 hi = f2us(h); float hif = us2f(hi); u16 lo = f2us(h - hif);
        bF[(t>>5)*640 + bb*40 + (t&31)] = hi;
        bF[(t>>5)*640 + (bb+8)*40 + (t&31)] = lo;
      }
    }
    if (s < Kc-1){
      bF[(5+(i0>>5))*640 + bb0*40 + (i0&31)] = f2us(xp0);
      if (v1ok) bF[(5+(i1>>5))*640 + bb1*40 + (i1&31)] = f2us(xp1);
    }
  }
  #pragma unroll
  for (int q=0;q<3;q++){
    int task = tid + q*512;
    if (task < 1200){
      int t = task >> 3, bb = task & 7;
      out[((size_t)(b0+bb)*Kc + kk)*Hc + t] = hst[q];
    }
  }
}

extern "C" void kernel_launch(void* const* d_in, const int* in_sizes, int n_in,
                              void* d_out, int out_size, void* d_ws, size_t ws_size,
                              hipStream_t stream){
  const float* x        = (const float*)d_in[0];
  const float* y        = (const float*)d_in[1];
  const float* z_noise  = (const float*)d_in[2];
  const float* lin_w    = (const float*)d_in[3];
  const float* lin_b    = (const float*)d_in[4];
  const float* a        = (const float*)d_in[5];
  const float* bias     = (const float*)d_in[6];
  const float* gl_wih   = (const float*)d_in[7];
  const float* gl_whh   = (const float*)d_in[8];
  const float* gl_bih   = (const float*)d_in[9];
  const float* gl_bhh   = (const float*)d_in[10];
  const float* mu_w     = (const float*)d_in[11];
  const float* mu_b     = (const float*)d_in[12];
  const float* std_w    = (const float*)d_in[13];
  const float* std_b    = (const float*)d_in[14];
  const float* net_wih  = (const float*)d_in[15];
  const float* net_whh  = (const float*)d_in[16];
  const float* net_bih  = (const float*)d_in[17];
  const float* net_bhh  = (const float*)d_in[18];
  float* ws = (float*)d_ws;
  float* out = (float*)d_out;

  wx_kernel<<<(Bc*KWc+255)/256, 256, 0, stream>>>(x, lin_w, lin_b, ws);
  attn_kernel<<<Bc*Kc, 256, 0, stream>>>(y, a, bias, ws);
  glproj_kernel<<<(Kc*Bc*H3c+255)/256, 256, 0, stream>>>(gl_wih, gl_bih, ws);
  glgru4_kernel<<<Bc, 1024, 0, stream>>>(gl_whh, gl_bhh, z_noise, mu_w, mu_b, std_w, std_b, ws);
  causes3_kernel<<<Kc*4, 512, 0, stream>>>(net_wih, net_whh, net_bih, net_bhh, ws, out);
}